// Round 13
// baseline (1254.126 us; speedup 1.0000x reference)
//
#include <hip/hip_runtime.h>
#include <math.h>

#define NN 50000
#define NE 200000
#define NH 4
#define NG 100
#define EPSBN 1e-5f
#define SLOPE 0.2f

typedef __attribute__((ext_vector_type(8))) short bf16x8;
typedef __attribute__((ext_vector_type(4))) float f32x4;

union U8 { bf16x8 v; uint4 q; unsigned w[4]; };

__device__ __forceinline__ unsigned short f2bf(float f) {
    unsigned u = __float_as_uint(f);
    unsigned r = (u + 0x7fffu + ((u >> 16) & 1u)) >> 16;   // RNE
    return (unsigned short)r;
}
__device__ __forceinline__ float bf2f(unsigned short s) {
    return __uint_as_float(((unsigned)s) << 16);
}

__global__ void fill_val(float* p, int n, float v) {
    int i = blockIdx.x * 256 + threadIdx.x;
    if (i < n) p[i] = v;
}

// ================= weight prep (verbatim r12) =================
__global__ void wprep1t(const float* __restrict__ Wl, const float* __restrict__ Wr,
                        unsigned short* __restrict__ Bh, unsigned short* __restrict__ Bl) {
    int idx = blockIdx.x * 256 + threadIdx.x;   // 524288
    int n = idx & 511, k = (idx >> 9) & 255, h = idx >> 17;
    const float* W = (n < 256) ? Wl : Wr;
    float w = W[(size_t)k * 1024 + h * 256 + (n & 255)];
    size_t dst = (size_t)h * 131072 + (((size_t)(n >> 4) * 8 + (k >> 5)) << 9)
               + ((((k >> 3) & 3) << 4) + (n & 15)) * 8 + (k & 7);
    unsigned u = __float_as_uint(w);
    Bh[dst] = (unsigned short)(u >> 16);                       // trunc hi
    Bl[dst] = f2bf(w - __uint_as_float(u & 0xFFFF0000u));      // RNE lo
}
__global__ void wprep2t(const float* __restrict__ Wl, const float* __restrict__ Wr,
                        unsigned short* __restrict__ Bh) {
    int idx = blockIdx.x * 256 + threadIdx.x;   // 524288
    int n = idx >> 10, k = idx & 1023;
    const float* W = (n < 256) ? Wl : Wr;
    float w = W[(size_t)k * 256 + (n & 255)];
    size_t dst = (((size_t)(n >> 4) * 32 + (k >> 5)) << 9)
               + ((((k >> 3) & 3) << 4) + (n & 15)) * 8 + (k & 7);
    Bh[dst] = f2bf(w);
}

__device__ __forceinline__ void cvt_split(const float4& v0, const float4& v1,
                                          bf16x8& h, bf16x8& l) {
    float vv[8];
    *(float4*)&vv[0] = v0; *(float4*)&vv[4] = v1;
    U8 uh, ul;
#pragma unroll
    for (int j = 0; j < 4; ++j) {
        float a0 = vv[2 * j], a1 = vv[2 * j + 1];
        unsigned u0 = __float_as_uint(a0), u1 = __float_as_uint(a1);
        uh.w[j] = (u0 >> 16) | (u1 & 0xFFFF0000u);             // trunc hi pair
        float l0 = a0 - __uint_as_float(u0 & 0xFFFF0000u);
        float l1 = a1 - __uint_as_float(u1 & 0xFFFF0000u);
        ul.w[j] = (unsigned)f2bf(l0) | ((unsigned)f2bf(l1) << 16);
    }
    h = uh.v; l = ul.v;
}

// ================= split-bf16 MFMA GEMM: 4 m-frags + A prefetch =================
// Block = 512 thr = 8 waves; wave w owns rows [m0+64w,+64) (4 m-frags) x 4 n-frags
// (64 cols); block = 512 rows x 64 cols. launch_bounds(512,2) -> 4 waves/SIMD,
// <=512 regs/wave budget: acc 64 AGPR + cur/next A (~64 VGPR) fit without spill
// (r12's 2-frag shape left MFMA cluster at 128 cyc < L2 latency -> 14% MfmaUtil;
// r11's 4-frag shape had no prefetch at 64 VGPR -> 26%. This combines both.)
// MODE 0: A f32 split in-reg, 3 passes, K=256, both B planes in LDS (64 KB).
// MODE 1: A bf16-hi, 1 pass, K=1024, B-hi in LDS (32 KB).
// Strip-clustered grid: p -> strip=((p>>6)<<3)+(p&7), slice=(p>>3)&7.
template<int MODE>
__launch_bounds__(512, 2)
__global__ void gemm_bs(const float* __restrict__ Af,
                        const unsigned short* __restrict__ A2, int lda,
                        const unsigned short* __restrict__ Bh,
                        const unsigned short* __restrict__ Bl, int KT,
                        const float* __restrict__ bL, const float* __restrict__ bR,
                        float* __restrict__ C, int M) {
    __shared__ unsigned short Bs[(MODE == 0 ? 2 : 1)][16384];
    const int p = blockIdx.x;
    const int strip = ((p >> 6) << 3) + (p & 7);
    if (strip * 512 >= M) return;             // padded tail
    const int slice = (p >> 3) & 7;
    const int m0 = strip * 512;
    const int tid = threadIdx.x;
    const int lane = tid & 63, w = tid >> 6;
    const int r15 = lane & 15, kq = lane >> 4;
    const size_t sliceBase = (size_t)slice * 4 * KT * 64;   // uint4 units/plane

    f32x4 acc[4][4];
#pragma unroll
    for (int m = 0; m < 4; ++m)
#pragma unroll
        for (int n = 0; n < 4; ++n) acc[m][n] = (f32x4){0.f, 0.f, 0.f, 0.f};

    const float* aPtr[4];
    const unsigned short* a2Ptr[4];
#pragma unroll
    for (int m = 0; m < 4; ++m) {
        int row = m0 + w * 64 + m * 16 + r15;
        row = row < M ? row : M - 1;
        if (MODE == 0) aPtr[m] = Af + (size_t)row * lda + kq * 8;
        else           a2Ptr[m] = A2 + (size_t)row * lda + kq * 8;
    }

    // ---- prime A pipeline (kt = 0) ----
    float4 curA[4][2];
    bf16x8 curH[4];
    if (MODE == 0) {
#pragma unroll
        for (int m = 0; m < 4; ++m) {
            curA[m][0] = *(const float4*)(aPtr[m]);
            curA[m][1] = *(const float4*)(aPtr[m] + 4);
        }
    } else {
#pragma unroll
        for (int m = 0; m < 4; ++m)
            curH[m] = *(const bf16x8*)(a2Ptr[m]);
    }

    const int nchunks = KT / 8;
    for (int kc = 0; kc < nchunks; ++kc) {
        // ---- fill B LDS for this 8-ktile chunk ----
        {
            const uint4* gh = (const uint4*)Bh + sliceBase;
            uint4* lh = (uint4*)&Bs[0][0];
#pragma unroll
            for (int i = 0; i < 4; ++i) {
                int u = i * 512 + tid;
                int nt = u >> 9;
                int ktl = (u & 511) >> 6, j = u & 63;
                size_t gix = ((size_t)nt * KT + kc * 8 + ktl) * 64 + j;
                lh[u] = gh[gix];
                if (MODE == 0)
                    ((uint4*)&Bs[1][0])[u] = ((const uint4*)Bl + sliceBase)[gix];
            }
        }
        __syncthreads();

#pragma unroll
        for (int ktl = 0; ktl < 8; ++ktl) {
            const int kt = kc * 8 + ktl;
            // ---- issue next-kt A loads before this kt's MFMA cluster ----
            float4 nxtA[4][2];
            bf16x8 nxtH[4];
            const bool hasNext = (kt + 1 < KT);
            if (hasNext) {
                if (MODE == 0) {
#pragma unroll
                    for (int m = 0; m < 4; ++m) {
                        nxtA[m][0] = *(const float4*)(aPtr[m] + (size_t)(kt + 1) * 32);
                        nxtA[m][1] = *(const float4*)(aPtr[m] + (size_t)(kt + 1) * 32 + 4);
                    }
                } else {
#pragma unroll
                    for (int m = 0; m < 4; ++m)
                        nxtH[m] = *(const bf16x8*)(a2Ptr[m] + (size_t)(kt + 1) * 32);
                }
            }
            // ---- convert current (MODE 0) ----
            bf16x8 ah[4], al[4];
            if (MODE == 0) {
#pragma unroll
                for (int m = 0; m < 4; ++m)
                    cvt_split(curA[m][0], curA[m][1], ah[m], al[m]);
            } else {
#pragma unroll
                for (int m = 0; m < 4; ++m) ah[m] = curH[m];
            }
            // ---- MFMA cluster ----
#pragma unroll
            for (int n = 0; n < 4; ++n) {
                bf16x8 bh = *(const bf16x8*)&Bs[0][(n * 8 + ktl) * 512 + lane * 8];
#pragma unroll
                for (int m = 0; m < 4; ++m)
                    acc[m][n] = __builtin_amdgcn_mfma_f32_16x16x32_bf16(
                        ah[m], bh, acc[m][n], 0, 0, 0);
                if (MODE == 0) {
                    bf16x8 bl = *(const bf16x8*)&Bs[1][(n * 8 + ktl) * 512 + lane * 8];
#pragma unroll
                    for (int m = 0; m < 4; ++m) {
                        acc[m][n] = __builtin_amdgcn_mfma_f32_16x16x32_bf16(
                            al[m], bh, acc[m][n], 0, 0, 0);
                        acc[m][n] = __builtin_amdgcn_mfma_f32_16x16x32_bf16(
                            ah[m], bl, acc[m][n], 0, 0, 0);
                    }
                }
            }
            // ---- rotate pipeline ----
            if (hasNext) {
                if (MODE == 0) {
#pragma unroll
                    for (int m = 0; m < 4; ++m) {
                        curA[m][0] = nxtA[m][0];
                        curA[m][1] = nxtA[m][1];
                    }
                } else {
#pragma unroll
                    for (int m = 0; m < 4; ++m) curH[m] = nxtH[m];
                }
            }
        }
        __syncthreads();
    }
    // ---- epilogue: C/D col=lane&15, row=(lane>>4)*4+reg (verified r4-r12) ----
#pragma unroll
    for (int n = 0; n < 4; ++n) {
        int gcol = slice * 64 + n * 16 + r15;
        float bv = (gcol < 256) ? bL[gcol] : bR[gcol - 256];
#pragma unroll
        for (int m = 0; m < 4; ++m) {
#pragma unroll
            for (int r = 0; r < 4; ++r) {
                int grow = m0 + w * 64 + m * 16 + kq * 4 + r;
                if (grow < M)
                    C[(size_t)grow * 512 + gcol] = acc[m][n][r] + bv;
            }
        }
    }
}

// ================= CSR build over dst (verified r5-r12) =================
__global__ void csr_count(const int* __restrict__ ei, int* __restrict__ cnt) {
    int e = blockIdx.x * 256 + threadIdx.x;
    if (e < NE) atomicAdd(&cnt[ei[NE + e]], 1);
}
__launch_bounds__(1024)
__global__ void csr_offsets(const int* __restrict__ cnt, int* __restrict__ off,
                            int* __restrict__ cursor) {
    __shared__ int s[1024];
    const int t = threadIdx.x;
    const int PER = 49;
    const int base = t * PER;
    int sum = 0;
    for (int i = 0; i < PER; ++i) {
        int idx = base + i;
        if (idx < NN) sum += cnt[idx];
    }
    s[t] = sum;
    __syncthreads();
    for (int d = 1; d < 1024; d <<= 1) {
        int v = (t >= d) ? s[t - d] : 0;
        __syncthreads();
        s[t] += v;
        __syncthreads();
    }
    int run = s[t] - sum;
    for (int i = 0; i < PER; ++i) {
        int idx = base + i;
        if (idx < NN) {
            off[idx] = run;
            cursor[idx] = run;
            run += cnt[idx];
            if (idx == NN - 1) off[NN] = run;
        }
    }
}
__global__ void csr_fill(const int* __restrict__ ei, int* __restrict__ cursor,
                         int* __restrict__ eidl) {
    int e = blockIdx.x * 256 + threadIdx.x;
    if (e < NE) {
        int d = ei[NE + e];
        int p = atomicAdd(&cursor[d], 1);
        eidl[p] = e;
    }
}

// ---------- per-edge logit partial (verbatim r6) ----------
__device__ __forceinline__ float edge_part(const float4& l, const float4& r,
                                           const float* ev, const float (*rW)[4],
                                           const float4& attv) {
    const float* lp = &l.x; const float* rp = &r.x; const float* ap = &attv.x;
    float part = 0.f;
#pragma unroll
    for (int j = 0; j < 4; ++j) {
        float ecf = 0.f;
#pragma unroll
        for (int d = 0; d < 12; ++d) ecf = fmaf(ev[d], rW[d][j], ecf);
        float mv = lp[j] + rp[j] + ecf;
        mv = mv > 0.f ? mv : SLOPE * mv;
        part = fmaf(mv, ap[j], part);
    }
    return part;
}

// ---------- fused node pass (verbatim r9-r12) ----------
template<int NHEADS, bool OUTHI>
__launch_bounds__(256)
__global__ void node_fused(float* __restrict__ xlr,
                           const int* __restrict__ off, const int* __restrict__ eidl,
                           const int* __restrict__ ei, const float* __restrict__ ea,
                           const float* __restrict__ We, int ldwe,
                           const float* __restrict__ att,
                           const float* __restrict__ bias, const float* __restrict__ gam,
                           const float* __restrict__ bet, const float* __restrict__ mu,
                           const float* __restrict__ var,
                           unsigned short* __restrict__ h1hi, int hcol) {
    const int n = blockIdx.x * 4 + (threadIdx.x >> 6);
    const int lane = threadIdx.x & 63;
    const int cf = lane * 4;
    float rW[12][4];
#pragma unroll
    for (int d = 0; d < 12; ++d) {
        float4 w = *(const float4*)&We[(size_t)d * ldwe + cf];
        rW[d][0] = w.x; rW[d][1] = w.y; rW[d][2] = w.z; rW[d][3] = w.w;
    }
    const float4 attv = *(const float4*)&att[cf];
    float* xrow = xlr + (size_t)n * 512;
    const float4 xr4 = *(const float4*)(xrow + 256 + cf);
    float acc[4] = {0.f, 0.f, 0.f, 0.f};
    float den = 0.f;
    const int beg = off[n], end = off[n + 1];
    constexpr int RED = 64 / NHEADS;
    int k = beg;
    for (; k + 2 <= end; k += 2) {
        int e0 = eidl[k], e1 = eidl[k + 1];
        int s0 = ei[e0], s1 = ei[e1];
        float ev0[12], ev1[12];
        const float2* p0 = (const float2*)(ea + (size_t)e0 * 12);
        const float2* p1 = (const float2*)(ea + (size_t)e1 * 12);
#pragma unroll
        for (int d = 0; d < 6; ++d) {
            float2 a = p0[d], b = p1[d];
            ev0[2 * d] = a.x; ev0[2 * d + 1] = a.y;
            ev1[2 * d] = b.x; ev1[2 * d + 1] = b.y;
        }
        float4 l0 = *(const float4*)(xlr + (size_t)s0 * 512 + cf);
        float4 l1 = *(const float4*)(xlr + (size_t)s1 * 512 + cf);
        float pa = edge_part(l0, xr4, ev0, rW, attv);
        float pb = edge_part(l1, xr4, ev1, rW, attv);
#pragma unroll
        for (int o = RED / 2; o > 0; o >>= 1) {
            pa += __shfl_xor(pa, o);
            pb += __shfl_xor(pb, o);
        }
        float ex0 = __expf(pa), ex1 = __expf(pb);
        den += ex0 + ex1;
        const float* lp0 = &l0.x; const float* lp1 = &l1.x;
#pragma unroll
        for (int j = 0; j < 4; ++j)
            acc[j] = fmaf(ex0, lp0[j], fmaf(ex1, lp1[j], acc[j]));
    }
    if (k < end) {
        int e0 = eidl[k];
        int s0 = ei[e0];
        float ev0[12];
        const float2* p0 = (const float2*)(ea + (size_t)e0 * 12);
#pragma unroll
        for (int d = 0; d < 6; ++d) {
            float2 a = p0[d];
            ev0[2 * d] = a.x; ev0[2 * d + 1] = a.y;
        }
        float4 l0 = *(const float4*)(xlr + (size_t)s0 * 512 + cf);
        float pa = edge_part(l0, xr4, ev0, rW, attv);
#pragma unroll
        for (int o = RED / 2; o > 0; o >>= 1) pa += __shfl_xor(pa, o);
        float ex0 = __expf(pa);
        den += ex0;
        const float* lp0 = &l0.x;
#pragma unroll
        for (int j = 0; j < 4; ++j) acc[j] = fmaf(ex0, lp0[j], acc[j]);
    }
    const float inv = 1.f / (den + 1e-16f);
    float o[4];
#pragma unroll
    for (int j = 0; j < 4; ++j) {
        int c = cf + j;
        float t = fmaxf(acc[j] * inv + bias[c], 0.f);
        o[j] = (t - mu[c]) * rsqrtf(var[c] + EPSBN) * gam[c] + bet[c];
    }
    if (OUTHI) {
        ushort4 hv;
        hv.x = f2bf(o[0]); hv.y = f2bf(o[1]); hv.z = f2bf(o[2]); hv.w = f2bf(o[3]);
        *(ushort4*)(h1hi + (size_t)n * 1024 + hcol + cf) = hv;
    } else {
        *(float4*)(xrow + 256 + cf) = make_float4(o[0], o[1], o[2], o[3]);
    }
}

// ================= head MLP =================
__launch_bounds__(64)
__global__ void head_mlp(const float* __restrict__ h2, const int* __restrict__ n_nodes,
                         const float* __restrict__ Wf1, const float* __restrict__ bf1,
                         const float* __restrict__ Wf2, const float* __restrict__ bf2,
                         float* __restrict__ out) {
    const int g = blockIdx.x;
    const int t = threadIdx.x;
    int acc = 0;
    for (int i = t; i <= g; i += 64) acc += n_nodes[i];
#pragma unroll
    for (int off = 32; off > 0; off >>= 1) acc += __shfl_xor(acc, off);
    const int node = acc - 1;
    __shared__ float row[256];
    for (int i = t; i < 256; i += 64) row[i] = h2[(size_t)node * 512 + 256 + i];
    __syncthreads();
    float hid = bf1[t];
    for (int k = 0; k < 256; ++k) hid = fmaf(row[k], Wf1[k * 64 + t], hid);
    hid = fmaxf(hid, 0.f);
    float p = hid * Wf2[t];
#pragma unroll
    for (int off = 32; off > 0; off >>= 1) p += __shfl_xor(p, off);
    if (t == 0) out[g] = p + bf2[0];
}

extern "C" void kernel_launch(void* const* d_in, const int* in_sizes, int n_in,
                              void* d_out, int out_size, void* d_ws, size_t ws_size,
                              hipStream_t stream) {
    const float* x   = (const float*)d_in[0];
    const int*   ei  = (const int*)d_in[1];
    const float* ea  = (const float*)d_in[2];
    const int*   nnd = (const int*)d_in[3];
    const float* Wl1 = (const float*)d_in[4];
    const float* bl1 = (const float*)d_in[5];
    const float* Wr1 = (const float*)d_in[6];
    const float* br1 = (const float*)d_in[7];
    const float* We1 = (const float*)d_in[8];
    const float* att1= (const float*)d_in[9];
    const float* b1  = (const float*)d_in[10];
    const float* g1  = (const float*)d_in[11];
    const float* be1 = (const float*)d_in[12];
    const float* m1  = (const float*)d_in[13];
    const float* v1  = (const float*)d_in[14];
    const float* Wl2 = (const float*)d_in[15];
    const float* bl2 = (const float*)d_in[16];
    const float* Wr2 = (const float*)d_in[17];
    const float* br2 = (const float*)d_in[18];
    const float* We2 = (const float*)d_in[19];
    const float* att2= (const float*)d_in[20];
    const float* b2  = (const float*)d_in[21];
    const float* g2  = (const float*)d_in[22];
    const float* be2 = (const float*)d_in[23];
    const float* m2  = (const float*)d_in[24];
    const float* v2  = (const float*)d_in[25];
    const float* Wf1 = (const float*)d_in[26];
    const float* bf1 = (const float*)d_in[27];
    const float* Wf2 = (const float*)d_in[28];
    const float* bf2 = (const float*)d_in[29];
    float* out = (float*)d_out;

    // ---- workspace (~208.7 MB; proven >= 212.8 MB) ----
    const size_t XB  = (size_t)NN * 512 * 4;       // 102.4 MB panel
    const size_t HB  = (size_t)NN * 1024 * 2;      // 102.4 MB h1 bf16-hi
    const size_t WPB = (size_t)524288 * 2;         // 1 MB per split plane
    char* ws = (char*)d_ws;
    size_t off = 0;
    float* xlr  = (float*)(ws + off); off += XB;   // L1 panel; later xlr2 (L2 out)
    unsigned short* h1hi = (unsigned short*)(ws + off); off += HB;
    unsigned short* B1h = (unsigned short*)(ws + off); off += WPB;
    unsigned short* B1l = (unsigned short*)(ws + off); off += WPB;
    unsigned short* B2h = (unsigned short*)(ws + off); off += WPB;
    int* cnt    = (int*)(ws + off); off += (size_t)NN * 4;
    int* csroff = (int*)(ws + off); off += ((size_t)(NN + 1) * 4 + 15) & ~15ull;
    int* cursor = (int*)(ws + off); off += (size_t)NN * 4;
    int* eidl   = (int*)(ws + off); off += (size_t)NE * 4;
    if (ws_size < off) {
        fill_val<<<(out_size + 255) / 256, 256, 0, stream>>>(out, out_size, 1e30f);
        return;
    }
    float* xlr2 = xlr;   // alias: xlr dead after last node_fused<1>

    // ---- CSR build (once) ----
    hipMemsetAsync(cnt, 0, (size_t)NN * 4, stream);
    csr_count<<<(NE + 255) / 256, 256, 0, stream>>>(ei, cnt);
    csr_offsets<<<1, 1024, 0, stream>>>(cnt, csroff, cursor);
    csr_fill<<<(NE + 255) / 256, 256, 0, stream>>>(ei, cursor, eidl);

    // ---- weight prep ----
    wprep1t<<<2048, 256, 0, stream>>>(Wl1, Wr1, B1h, B1l);
    wprep2t<<<2048, 256, 0, stream>>>(Wl2, Wr2, B2h);

    // strip-clustered 1D grid: 98 strips of 512 rows -> pad to 104 (13 groups of 8)
    const int gemmBlocks = 13 * 64;   // 832
    const int nodeBlocks = NN / 4;

    // ================= layer 1, per head =================
    for (int h = 0; h < NH; ++h) {
        gemm_bs<0><<<gemmBlocks, 512, 0, stream>>>(
            x, nullptr, 256, B1h + (size_t)h * 131072, B1l + (size_t)h * 131072, 8,
            bl1 + h * 256, br1 + h * 256, xlr, NN);
        node_fused<1, true><<<nodeBlocks, 256, 0, stream>>>(
            xlr, csroff, eidl, ei, ea, We1 + h * 256, 1024, att1 + h * 256,
            b1 + h * 256, g1 + h * 256, be1 + h * 256, m1 + h * 256, v1 + h * 256,
            h1hi, h * 256);
    }

    // ================= layer 2: single K=1024, single-pass GEMM =================
    gemm_bs<1><<<gemmBlocks, 512, 0, stream>>>(
        nullptr, h1hi, 1024, B2h, nullptr, 32, bl2, br2, xlr2, NN);
    node_fused<4, false><<<nodeBlocks, 256, 0, stream>>>(
        xlr2, csroff, eidl, ei, ea, We2, 256, att2, b2, g2, be2, m2, v2,
        nullptr, 0);

    head_mlp<<<NG, 64, 0, stream>>>(xlr2, nnd, Wf1, bf1, Wf2, bf2, out);
}

// Round 14
// 1024.171 us; speedup vs baseline: 1.2245x; 1.2245x over previous
//
#include <hip/hip_runtime.h>
#include <math.h>

#define NN 50000
#define NE 200000
#define NH 4
#define NG 100
#define EPSBN 1e-5f
#define SLOPE 0.2f

typedef __attribute__((ext_vector_type(8))) short bf16x8;
typedef __attribute__((ext_vector_type(4))) float f32x4;

union U8 { bf16x8 v; uint4 q; unsigned w[4]; };

__device__ __forceinline__ unsigned short f2bf(float f) {
    unsigned u = __float_as_uint(f);
    unsigned r = (u + 0x7fffu + ((u >> 16) & 1u)) >> 16;   // RNE
    return (unsigned short)r;
}
__device__ __forceinline__ float bf2f(unsigned short s) {
    return __uint_as_float(((unsigned)s) << 16);
}

__global__ void fill_val(float* p, int n, float v) {
    int i = blockIdx.x * 256 + threadIdx.x;
    if (i < n) p[i] = v;
}

// ================= weight prep (verbatim r12) =================
__global__ void wprep1t(const float* __restrict__ Wl, const float* __restrict__ Wr,
                        unsigned short* __restrict__ Bh, unsigned short* __restrict__ Bl) {
    int idx = blockIdx.x * 256 + threadIdx.x;   // 524288
    int n = idx & 511, k = (idx >> 9) & 255, h = idx >> 17;
    const float* W = (n < 256) ? Wl : Wr;
    float w = W[(size_t)k * 1024 + h * 256 + (n & 255)];
    size_t dst = (size_t)h * 131072 + (((size_t)(n >> 4) * 8 + (k >> 5)) << 9)
               + ((((k >> 3) & 3) << 4) + (n & 15)) * 8 + (k & 7);
    unsigned u = __float_as_uint(w);
    Bh[dst] = (unsigned short)(u >> 16);                       // trunc hi
    Bl[dst] = f2bf(w - __uint_as_float(u & 0xFFFF0000u));      // RNE lo
}
__global__ void wprep2t(const float* __restrict__ Wl, const float* __restrict__ Wr,
                        unsigned short* __restrict__ Bh) {
    int idx = blockIdx.x * 256 + threadIdx.x;   // 524288
    int n = idx >> 10, k = idx & 1023;
    const float* W = (n < 256) ? Wl : Wr;
    float w = W[(size_t)k * 256 + (n & 255)];
    size_t dst = (((size_t)(n >> 4) * 32 + (k >> 5)) << 9)
               + ((((k >> 3) & 3) << 4) + (n & 15)) * 8 + (k & 7);
    Bh[dst] = f2bf(w);
}

__device__ __forceinline__ void cvt_split(const float4& v0, const float4& v1,
                                          bf16x8& h, bf16x8& l) {
    float vv[8];
    *(float4*)&vv[0] = v0; *(float4*)&vv[4] = v1;
    U8 uh, ul;
#pragma unroll
    for (int j = 0; j < 4; ++j) {
        float a0 = vv[2 * j], a1 = vv[2 * j + 1];
        unsigned u0 = __float_as_uint(a0), u1 = __float_as_uint(a1);
        uh.w[j] = (u0 >> 16) | (u1 & 0xFFFF0000u);             // trunc hi pair
        float l0 = a0 - __uint_as_float(u0 & 0xFFFF0000u);
        float l1 = a1 - __uint_as_float(u1 & 0xFFFF0000u);
        ul.w[j] = (unsigned)f2bf(l0) | ((unsigned)f2bf(l1) << 16);
    }
    h = uh.v; l = ul.v;
}

// ================= split-bf16 MFMA GEMM (r12 structure, proven best) =================
// Block = 512 thr = 8 waves; wave w: rows [m0+32w,+32) (2 m-frags) x 4 n-frags.
// launch_bounds(512,4) + 1-deep A prefetch (r12: MODE1 146us, best of r8-r13 family).
// MODE 0: A f32 split in-reg, 3 passes, K=256, both B planes in LDS (64 KB),
//         C = bf16 interleaved [row][512] (r14: halves write + node gather bytes).
// MODE 1: A bf16-hi, 1 pass, K=1024, B-hi in LDS (32 KB), C = f32 [row][512].
// Strip-clustered grid: p -> strip=((p>>6)<<3)+(p&7), slice=(p>>3)&7.
template<int MODE>
__launch_bounds__(512, 4)
__global__ void gemm_bs(const float* __restrict__ Af,
                        const unsigned short* __restrict__ A2, int lda,
                        const unsigned short* __restrict__ Bh,
                        const unsigned short* __restrict__ Bl, int KT,
                        const float* __restrict__ bL, const float* __restrict__ bR,
                        void* __restrict__ Cv, int M) {
    __shared__ unsigned short Bs[(MODE == 0 ? 2 : 1)][16384];
    const int p = blockIdx.x;
    const int strip = ((p >> 6) << 3) + (p & 7);
    if (strip * 256 >= M) return;             // padded tail
    const int slice = (p >> 3) & 7;
    const int m0 = strip * 256;
    const int tid = threadIdx.x;
    const int lane = tid & 63, w = tid >> 6;
    const int r15 = lane & 15, kq = lane >> 4;
    const size_t sliceBase = (size_t)slice * 4 * KT * 64;   // uint4 units/plane

    f32x4 acc[2][4];
#pragma unroll
    for (int m = 0; m < 2; ++m)
#pragma unroll
        for (int n = 0; n < 4; ++n) acc[m][n] = (f32x4){0.f, 0.f, 0.f, 0.f};

    const float* aPtr[2];
    const unsigned short* a2Ptr[2];
#pragma unroll
    for (int m = 0; m < 2; ++m) {
        int row = m0 + w * 32 + m * 16 + r15;
        row = row < M ? row : M - 1;
        if (MODE == 0) aPtr[m] = Af + (size_t)row * lda + kq * 8;
        else           a2Ptr[m] = A2 + (size_t)row * lda + kq * 8;
    }

    // ---- prime the A register pipeline (kt = 0) ----
    float4 curA[2][2];
    bf16x8 curH[2];
    if (MODE == 0) {
#pragma unroll
        for (int m = 0; m < 2; ++m) {
            curA[m][0] = *(const float4*)(aPtr[m]);
            curA[m][1] = *(const float4*)(aPtr[m] + 4);
        }
    } else {
#pragma unroll
        for (int m = 0; m < 2; ++m)
            curH[m] = *(const bf16x8*)(a2Ptr[m]);
    }

    const int nchunks = KT / 8;
    for (int kc = 0; kc < nchunks; ++kc) {
        // ---- fill B LDS for this 8-ktile chunk ----
        {
            const uint4* gh = (const uint4*)Bh + sliceBase;
            uint4* lh = (uint4*)&Bs[0][0];
#pragma unroll
            for (int i = 0; i < 4; ++i) {
                int u = i * 512 + tid;
                int nt = u >> 9;
                int ktl = (u & 511) >> 6, j = u & 63;
                size_t gix = ((size_t)nt * KT + kc * 8 + ktl) * 64 + j;
                lh[u] = gh[gix];
                if (MODE == 0)
                    ((uint4*)&Bs[1][0])[u] = ((const uint4*)Bl + sliceBase)[gix];
            }
        }
        __syncthreads();

#pragma unroll
        for (int ktl = 0; ktl < 8; ++ktl) {
            const int kt = kc * 8 + ktl;
            // ---- issue next-kt A loads before this kt's MFMA cluster ----
            float4 nxtA[2][2];
            bf16x8 nxtH[2];
            const bool hasNext = (kt + 1 < KT);
            if (hasNext) {
                if (MODE == 0) {
#pragma unroll
                    for (int m = 0; m < 2; ++m) {
                        nxtA[m][0] = *(const float4*)(aPtr[m] + (size_t)(kt + 1) * 32);
                        nxtA[m][1] = *(const float4*)(aPtr[m] + (size_t)(kt + 1) * 32 + 4);
                    }
                } else {
#pragma unroll
                    for (int m = 0; m < 2; ++m)
                        nxtH[m] = *(const bf16x8*)(a2Ptr[m] + (size_t)(kt + 1) * 32);
                }
            }
            // ---- convert current (MODE 0) ----
            bf16x8 ah[2], al[2];
            if (MODE == 0) {
#pragma unroll
                for (int m = 0; m < 2; ++m)
                    cvt_split(curA[m][0], curA[m][1], ah[m], al[m]);
            } else {
#pragma unroll
                for (int m = 0; m < 2; ++m) ah[m] = curH[m];
            }
            // ---- MFMA cluster ----
#pragma unroll
            for (int n = 0; n < 4; ++n) {
                bf16x8 bh = *(const bf16x8*)&Bs[0][(n * 8 + ktl) * 512 + lane * 8];
#pragma unroll
                for (int m = 0; m < 2; ++m)
                    acc[m][n] = __builtin_amdgcn_mfma_f32_16x16x32_bf16(
                        ah[m], bh, acc[m][n], 0, 0, 0);
                if (MODE == 0) {
                    bf16x8 bl = *(const bf16x8*)&Bs[1][(n * 8 + ktl) * 512 + lane * 8];
#pragma unroll
                    for (int m = 0; m < 2; ++m) {
                        acc[m][n] = __builtin_amdgcn_mfma_f32_16x16x32_bf16(
                            al[m], bh, acc[m][n], 0, 0, 0);
                        acc[m][n] = __builtin_amdgcn_mfma_f32_16x16x32_bf16(
                            ah[m], bl, acc[m][n], 0, 0, 0);
                    }
                }
            }
            // ---- rotate pipeline ----
            if (hasNext) {
                if (MODE == 0) {
#pragma unroll
                    for (int m = 0; m < 2; ++m) {
                        curA[m][0] = nxtA[m][0];
                        curA[m][1] = nxtA[m][1];
                    }
                } else {
#pragma unroll
                    for (int m = 0; m < 2; ++m) curH[m] = nxtH[m];
                }
            }
        }
        __syncthreads();
    }
    // ---- epilogue: C/D col=lane&15, row=(lane>>4)*4+reg (verified r4-r13) ----
#pragma unroll
    for (int n = 0; n < 4; ++n) {
        int gcol = slice * 64 + n * 16 + r15;
        float bv = (gcol < 256) ? bL[gcol] : bR[gcol - 256];
#pragma unroll
        for (int m = 0; m < 2; ++m) {
#pragma unroll
            for (int r = 0; r < 4; ++r) {
                int grow = m0 + w * 32 + m * 16 + kq * 4 + r;
                if (grow < M) {
                    if (MODE == 0)
                        ((unsigned short*)Cv)[(size_t)grow * 512 + gcol] =
                            f2bf(acc[m][n][r] + bv);
                    else
                        ((float*)Cv)[(size_t)grow * 512 + gcol] = acc[m][n][r] + bv;
                }
            }
        }
    }
}

// ================= CSR build over dst (verified r5-r13) =================
__global__ void csr_count(const int* __restrict__ ei, int* __restrict__ cnt) {
    int e = blockIdx.x * 256 + threadIdx.x;
    if (e < NE) atomicAdd(&cnt[ei[NE + e]], 1);
}
__launch_bounds__(1024)
__global__ void csr_offsets(const int* __restrict__ cnt, int* __restrict__ off,
                            int* __restrict__ cursor) {
    __shared__ int s[1024];
    const int t = threadIdx.x;
    const int PER = 49;
    const int base = t * PER;
    int sum = 0;
    for (int i = 0; i < PER; ++i) {
        int idx = base + i;
        if (idx < NN) sum += cnt[idx];
    }
    s[t] = sum;
    __syncthreads();
    for (int d = 1; d < 1024; d <<= 1) {
        int v = (t >= d) ? s[t - d] : 0;
        __syncthreads();
        s[t] += v;
        __syncthreads();
    }
    int run = s[t] - sum;
    for (int i = 0; i < PER; ++i) {
        int idx = base + i;
        if (idx < NN) {
            off[idx] = run;
            cursor[idx] = run;
            run += cnt[idx];
            if (idx == NN - 1) off[NN] = run;
        }
    }
}
__global__ void csr_fill(const int* __restrict__ ei, int* __restrict__ cursor,
                         int* __restrict__ eidl) {
    int e = blockIdx.x * 256 + threadIdx.x;
    if (e < NE) {
        int d = ei[NE + e];
        int p = atomicAdd(&cursor[d], 1);
        eidl[p] = e;
    }
}

// ---------- per-edge logit partial (verbatim r6) ----------
__device__ __forceinline__ float edge_part(const float4& l, const float4& r,
                                           const float* ev, const float (*rW)[4],
                                           const float4& attv) {
    const float* lp = &l.x; const float* rp = &r.x; const float* ap = &attv.x;
    float part = 0.f;
#pragma unroll
    for (int j = 0; j < 4; ++j) {
        float ecf = 0.f;
#pragma unroll
        for (int d = 0; d < 12; ++d) ecf = fmaf(ev[d], rW[d][j], ecf);
        float mv = lp[j] + rp[j] + ecf;
        mv = mv > 0.f ? mv : SLOPE * mv;
        part = fmaf(mv, ap[j], part);
    }
    return part;
}

// ---------- fused node pass; INBF16 = gather bf16 rows (r14) ----------
template<int NHEADS, bool OUTHI, bool INBF16>
__launch_bounds__(256)
__global__ void node_fused(const unsigned short* __restrict__ x16,
                           float* __restrict__ x32,
                           const int* __restrict__ off, const int* __restrict__ eidl,
                           const int* __restrict__ ei, const float* __restrict__ ea,
                           const float* __restrict__ We, int ldwe,
                           const float* __restrict__ att,
                           const float* __restrict__ bias, const float* __restrict__ gam,
                           const float* __restrict__ bet, const float* __restrict__ mu,
                           const float* __restrict__ var,
                           unsigned short* __restrict__ h1hi, int hcol) {
    const int n = blockIdx.x * 4 + (threadIdx.x >> 6);
    const int lane = threadIdx.x & 63;
    const int cf = lane * 4;
    float rW[12][4];
#pragma unroll
    for (int d = 0; d < 12; ++d) {
        float4 w = *(const float4*)&We[(size_t)d * ldwe + cf];
        rW[d][0] = w.x; rW[d][1] = w.y; rW[d][2] = w.z; rW[d][3] = w.w;
    }
    const float4 attv = *(const float4*)&att[cf];
    float4 xr4;
    if (INBF16) {
        ushort4 u = *(const ushort4*)(x16 + (size_t)n * 512 + 256 + cf);
        xr4 = make_float4(bf2f(u.x), bf2f(u.y), bf2f(u.z), bf2f(u.w));
    } else {
        xr4 = *(const float4*)(x32 + (size_t)n * 512 + 256 + cf);
    }
    float acc[4] = {0.f, 0.f, 0.f, 0.f};
    float den = 0.f;
    const int beg = off[n], end = off[n + 1];
    constexpr int RED = 64 / NHEADS;
    int k = beg;
    for (; k + 2 <= end; k += 2) {
        int e0 = eidl[k], e1 = eidl[k + 1];
        int s0 = ei[e0], s1 = ei[e1];
        float ev0[12], ev1[12];
        const float2* p0 = (const float2*)(ea + (size_t)e0 * 12);
        const float2* p1 = (const float2*)(ea + (size_t)e1 * 12);
#pragma unroll
        for (int d = 0; d < 6; ++d) {
            float2 a = p0[d], b = p1[d];
            ev0[2 * d] = a.x; ev0[2 * d + 1] = a.y;
            ev1[2 * d] = b.x; ev1[2 * d + 1] = b.y;
        }
        float4 l0, l1;
        if (INBF16) {
            ushort4 u0 = *(const ushort4*)(x16 + (size_t)s0 * 512 + cf);
            ushort4 u1 = *(const ushort4*)(x16 + (size_t)s1 * 512 + cf);
            l0 = make_float4(bf2f(u0.x), bf2f(u0.y), bf2f(u0.z), bf2f(u0.w));
            l1 = make_float4(bf2f(u1.x), bf2f(u1.y), bf2f(u1.z), bf2f(u1.w));
        } else {
            l0 = *(const float4*)(x32 + (size_t)s0 * 512 + cf);
            l1 = *(const float4*)(x32 + (size_t)s1 * 512 + cf);
        }
        float pa = edge_part(l0, xr4, ev0, rW, attv);
        float pb = edge_part(l1, xr4, ev1, rW, attv);
#pragma unroll
        for (int o = RED / 2; o > 0; o >>= 1) {
            pa += __shfl_xor(pa, o);
            pb += __shfl_xor(pb, o);
        }
        float ex0 = __expf(pa), ex1 = __expf(pb);
        den += ex0 + ex1;
        const float* lp0 = &l0.x; const float* lp1 = &l1.x;
#pragma unroll
        for (int j = 0; j < 4; ++j)
            acc[j] = fmaf(ex0, lp0[j], fmaf(ex1, lp1[j], acc[j]));
    }
    if (k < end) {
        int e0 = eidl[k];
        int s0 = ei[e0];
        float ev0[12];
        const float2* p0 = (const float2*)(ea + (size_t)e0 * 12);
#pragma unroll
        for (int d = 0; d < 6; ++d) {
            float2 a = p0[d];
            ev0[2 * d] = a.x; ev0[2 * d + 1] = a.y;
        }
        float4 l0;
        if (INBF16) {
            ushort4 u0 = *(const ushort4*)(x16 + (size_t)s0 * 512 + cf);
            l0 = make_float4(bf2f(u0.x), bf2f(u0.y), bf2f(u0.z), bf2f(u0.w));
        } else {
            l0 = *(const float4*)(x32 + (size_t)s0 * 512 + cf);
        }
        float pa = edge_part(l0, xr4, ev0, rW, attv);
#pragma unroll
        for (int o = RED / 2; o > 0; o >>= 1) pa += __shfl_xor(pa, o);
        float ex0 = __expf(pa);
        den += ex0;
        const float* lp0 = &l0.x;
#pragma unroll
        for (int j = 0; j < 4; ++j) acc[j] = fmaf(ex0, lp0[j], acc[j]);
    }
    const float inv = 1.f / (den + 1e-16f);
    float o[4];
#pragma unroll
    for (int j = 0; j < 4; ++j) {
        int c = cf + j;
        float t = fmaxf(acc[j] * inv + bias[c], 0.f);
        o[j] = (t - mu[c]) * rsqrtf(var[c] + EPSBN) * gam[c] + bet[c];
    }
    if (OUTHI) {
        ushort4 hv;
        hv.x = f2bf(o[0]); hv.y = f2bf(o[1]); hv.z = f2bf(o[2]); hv.w = f2bf(o[3]);
        *(ushort4*)(h1hi + (size_t)n * 1024 + hcol + cf) = hv;
    } else {
        *(float4*)(x32 + (size_t)n * 512 + 256 + cf) = make_float4(o[0], o[1], o[2], o[3]);
    }
}

// ================= head MLP =================
__launch_bounds__(64)
__global__ void head_mlp(const float* __restrict__ h2, const int* __restrict__ n_nodes,
                         const float* __restrict__ Wf1, const float* __restrict__ bf1,
                         const float* __restrict__ Wf2, const float* __restrict__ bf2,
                         float* __restrict__ out) {
    const int g = blockIdx.x;
    const int t = threadIdx.x;
    int acc = 0;
    for (int i = t; i <= g; i += 64) acc += n_nodes[i];
#pragma unroll
    for (int off = 32; off > 0; off >>= 1) acc += __shfl_xor(acc, off);
    const int node = acc - 1;
    __shared__ float row[256];
    for (int i = t; i < 256; i += 64) row[i] = h2[(size_t)node * 512 + 256 + i];
    __syncthreads();
    float hid = bf1[t];
    for (int k = 0; k < 256; ++k) hid = fmaf(row[k], Wf1[k * 64 + t], hid);
    hid = fmaxf(hid, 0.f);
    float p = hid * Wf2[t];
#pragma unroll
    for (int off = 32; off > 0; off >>= 1) p += __shfl_xor(p, off);
    if (t == 0) out[g] = p + bf2[0];
}

extern "C" void kernel_launch(void* const* d_in, const int* in_sizes, int n_in,
                              void* d_out, int out_size, void* d_ws, size_t ws_size,
                              hipStream_t stream) {
    const float* x   = (const float*)d_in[0];
    const int*   ei  = (const int*)d_in[1];
    const float* ea  = (const float*)d_in[2];
    const int*   nnd = (const int*)d_in[3];
    const float* Wl1 = (const float*)d_in[4];
    const float* bl1 = (const float*)d_in[5];
    const float* Wr1 = (const float*)d_in[6];
    const float* br1 = (const float*)d_in[7];
    const float* We1 = (const float*)d_in[8];
    const float* att1= (const float*)d_in[9];
    const float* b1  = (const float*)d_in[10];
    const float* g1  = (const float*)d_in[11];
    const float* be1 = (const float*)d_in[12];
    const float* m1  = (const float*)d_in[13];
    const float* v1  = (const float*)d_in[14];
    const float* Wl2 = (const float*)d_in[15];
    const float* bl2 = (const float*)d_in[16];
    const float* Wr2 = (const float*)d_in[17];
    const float* br2 = (const float*)d_in[18];
    const float* We2 = (const float*)d_in[19];
    const float* att2= (const float*)d_in[20];
    const float* b2  = (const float*)d_in[21];
    const float* g2  = (const float*)d_in[22];
    const float* be2 = (const float*)d_in[23];
    const float* m2  = (const float*)d_in[24];
    const float* v2  = (const float*)d_in[25];
    const float* Wf1 = (const float*)d_in[26];
    const float* bf1 = (const float*)d_in[27];
    const float* Wf2 = (const float*)d_in[28];
    const float* bf2 = (const float*)d_in[29];
    float* out = (float*)d_out;

    // ---- workspace (~209.3 MB; proven >= 212.8 MB) ----
    // region X (102.4 MB): L1 phase -> xlr bf16 [50000][512] in first 51.2 MB;
    //                      L2 phase -> xlr2 f32 [50000][512] (xlr dead by then).
    const size_t XB  = (size_t)NN * 512 * 4;       // 102.4 MB
    const size_t HB  = (size_t)NN * 1024 * 2;      // 102.4 MB h1 bf16-hi
    const size_t WPB = (size_t)524288 * 2;         // 1 MB per split plane
    char* ws = (char*)d_ws;
    size_t off = 0;
    float* xlr2 = (float*)(ws + off); off += XB;
    unsigned short* xlr16 = (unsigned short*)xlr2;   // alias, L1 phase only
    unsigned short* h1hi = (unsigned short*)(ws + off); off += HB;
    unsigned short* B1h = (unsigned short*)(ws + off); off += WPB;
    unsigned short* B1l = (unsigned short*)(ws + off); off += WPB;
    unsigned short* B2h = (unsigned short*)(ws + off); off += WPB;
    int* cnt    = (int*)(ws + off); off += (size_t)NN * 4;
    int* csroff = (int*)(ws + off); off += ((size_t)(NN + 1) * 4 + 15) & ~15ull;
    int* cursor = (int*)(ws + off); off += (size_t)NN * 4;
    int* eidl   = (int*)(ws + off); off += (size_t)NE * 4;
    if (ws_size < off) {
        fill_val<<<(out_size + 255) / 256, 256, 0, stream>>>(out, out_size, 1e30f);
        return;
    }

    // ---- CSR build (once) ----
    hipMemsetAsync(cnt, 0, (size_t)NN * 4, stream);
    csr_count<<<(NE + 255) / 256, 256, 0, stream>>>(ei, cnt);
    csr_offsets<<<1, 1024, 0, stream>>>(cnt, csroff, cursor);
    csr_fill<<<(NE + 255) / 256, 256, 0, stream>>>(ei, cursor, eidl);

    // ---- weight prep ----
    wprep1t<<<2048, 256, 0, stream>>>(Wl1, Wr1, B1h, B1l);
    wprep2t<<<2048, 256, 0, stream>>>(Wl2, Wr2, B2h);

    // strip-clustered 1D grid: 196 strips of 256 rows -> pad to 200 (25 groups of 8)
    const int gemmBlocks = 25 * 64;   // 1600
    const int nodeBlocks = NN / 4;

    // ================= layer 1, per head =================
    for (int h = 0; h < NH; ++h) {
        gemm_bs<0><<<gemmBlocks, 512, 0, stream>>>(
            x, nullptr, 256, B1h + (size_t)h * 131072, B1l + (size_t)h * 131072, 8,
            bl1 + h * 256, br1 + h * 256, xlr16, NN);
        node_fused<1, true, true><<<nodeBlocks, 256, 0, stream>>>(
            xlr16, nullptr, csroff, eidl, ei, ea, We1 + h * 256, 1024, att1 + h * 256,
            b1 + h * 256, g1 + h * 256, be1 + h * 256, m1 + h * 256, v1 + h * 256,
            h1hi, h * 256);
    }

    // ================= layer 2: single K=1024, single-pass GEMM =================
    gemm_bs<1><<<gemmBlocks, 512, 0, stream>>>(
        nullptr, h1hi, 1024, B2h, nullptr, 32, bl2, br2, xlr2, NN);
    node_fused<4, false, false><<<nodeBlocks, 256, 0, stream>>>(
        nullptr, xlr2, csroff, eidl, ei, ea, We2, 256, att2, b2, g2, be2, m2, v2,
        nullptr, 0);

    head_mlp<<<NG, 64, 0, stream>>>(xlr2, nnd, Wf1, bf1, Wf2, bf2, out);
}

// Round 15
// 949.356 us; speedup vs baseline: 1.3210x; 1.0788x over previous
//
#include <hip/hip_runtime.h>
#include <math.h>

#define NN 50000
#define NE 200000
#define NH 4
#define NG 100
#define EPSBN 1e-5f
#define SLOPE 0.2f

typedef __attribute__((ext_vector_type(8))) short bf16x8;
typedef __attribute__((ext_vector_type(4))) float f32x4;

union U8 { bf16x8 v; uint4 q; unsigned w[4]; };

__device__ __forceinline__ unsigned short f2bf(float f) {
    unsigned u = __float_as_uint(f);
    unsigned r = (u + 0x7fffu + ((u >> 16) & 1u)) >> 16;   // RNE
    return (unsigned short)r;
}
__device__ __forceinline__ float bf2f(unsigned short s) {
    return __uint_as_float(((unsigned)s) << 16);
}

__global__ void fill_val(float* p, int n, float v) {
    int i = blockIdx.x * 256 + threadIdx.x;
    if (i < n) p[i] = v;
}

// ================= weight prep =================
// Fragment-tiled: short idx = ((n>>4)*(K/32) + (k>>5))*512 + (((k>>3)&3)*16 + (n&15))*8 + (k&7)
// L1 (per head, K=256): RNE bf16 only (r15: 2-pass GEMM, A-side split keeps accuracy)
__global__ void wprep1t(const float* __restrict__ Wl, const float* __restrict__ Wr,
                        unsigned short* __restrict__ Bh) {
    int idx = blockIdx.x * 256 + threadIdx.x;   // 524288
    int n = idx & 511, k = (idx >> 9) & 255, h = idx >> 17;
    const float* W = (n < 256) ? Wl : Wr;
    float w = W[(size_t)k * 1024 + h * 256 + (n & 255)];
    size_t dst = (size_t)h * 131072 + (((size_t)(n >> 4) * 8 + (k >> 5)) << 9)
               + ((((k >> 3) & 3) << 4) + (n & 15)) * 8 + (k & 7);
    Bh[dst] = f2bf(w);
}
// L2 (K=1024): RNE bf16
__global__ void wprep2t(const float* __restrict__ Wl, const float* __restrict__ Wr,
                        unsigned short* __restrict__ Bh) {
    int idx = blockIdx.x * 256 + threadIdx.x;   // 524288
    int n = idx >> 10, k = idx & 1023;
    const float* W = (n < 256) ? Wl : Wr;
    float w = W[(size_t)k * 256 + (n & 255)];
    size_t dst = (((size_t)(n >> 4) * 32 + (k >> 5)) << 9)
               + ((((k >> 3) & 3) << 4) + (n & 15)) * 8 + (k & 7);
    Bh[dst] = f2bf(w);
}

__device__ __forceinline__ void cvt_split(const float4& v0, const float4& v1,
                                          bf16x8& h, bf16x8& l) {
    float vv[8];
    *(float4*)&vv[0] = v0; *(float4*)&vv[4] = v1;
    U8 uh, ul;
#pragma unroll
    for (int j = 0; j < 4; ++j) {
        float a0 = vv[2 * j], a1 = vv[2 * j + 1];
        unsigned u0 = __float_as_uint(a0), u1 = __float_as_uint(a1);
        uh.w[j] = (u0 >> 16) | (u1 & 0xFFFF0000u);             // trunc hi pair
        float l0 = a0 - __uint_as_float(u0 & 0xFFFF0000u);
        float l1 = a1 - __uint_as_float(u1 & 0xFFFF0000u);
        ul.w[j] = (unsigned)f2bf(l0) | ((unsigned)f2bf(l1) << 16);
    }
    h = uh.v; l = ul.v;
}

// ================= MFMA GEMM (r12 skeleton; r15: tiled A for MODE1, bf16 C) =================
// Block = 512 thr = 8 waves; wave w: rows [m0+32w,+32) (2 m-frags) x 4 n-frags (64 cols).
// MODE 0: A = x f32 (trunc-hi/lo split in-reg), 2 passes (AhBh+AlBh), K=256.
// MODE 1: A = h1 in FRAGMENT-TILED bf16 (one contiguous 1KB load/wave/frag), 1 pass,
//         K=1024, 2-deep A prefetch.
// B-hi (RNE) in 32 KB LDS. C = bf16 interleaved [row][512].
// Strip-clustered grid: p -> strip=((p>>6)<<3)+(p&7), slice=(p>>3)&7 (A L2-shared).
template<int MODE>
__launch_bounds__(512, 4)
__global__ void gemm_bs(const float* __restrict__ Af,
                        const unsigned short* __restrict__ Atile,
                        const unsigned short* __restrict__ Bh, int KT,
                        const float* __restrict__ bL, const float* __restrict__ bR,
                        unsigned short* __restrict__ C, int M) {
    __shared__ unsigned short Bs[16384];      // 32 KB: [4nt][8kt][512]
    const int p = blockIdx.x;
    const int strip = ((p >> 6) << 3) + (p & 7);
    if (strip * 256 >= M) return;             // padded tail
    const int slice = (p >> 3) & 7;
    const int m0 = strip * 256;
    const int tid = threadIdx.x;
    const int lane = tid & 63, w = tid >> 6;
    const int r15 = lane & 15, kq = lane >> 4;
    const size_t sliceBase = (size_t)slice * 4 * KT * 64;   // uint4 units

    f32x4 acc[2][4];
#pragma unroll
    for (int m = 0; m < 2; ++m)
#pragma unroll
        for (int n = 0; n < 4; ++n) acc[m][n] = (f32x4){0.f, 0.f, 0.f, 0.f};

    const float* aPtr[2];
    const unsigned short* a2Ptr[2];
#pragma unroll
    for (int m = 0; m < 2; ++m) {
        if (MODE == 0) {
            int row = m0 + w * 32 + m * 16 + r15;
            row = row < M ? row : M - 1;
            aPtr[m] = Af + (size_t)row * 256 + kq * 8;
        } else {
            // row-tile index; pad tiles allocated (reads in-bounds, C rows discarded)
            a2Ptr[m] = Atile + (size_t)(strip * 16 + w * 2 + m) * 16384 + lane * 8;
        }
    }

    // ---- prime A pipeline ----
    float4 curA[2][2];
    bf16x8 curH[2], midH[2];
    if (MODE == 0) {
#pragma unroll
        for (int m = 0; m < 2; ++m) {
            curA[m][0] = *(const float4*)(aPtr[m]);
            curA[m][1] = *(const float4*)(aPtr[m] + 4);
        }
    } else {
#pragma unroll
        for (int m = 0; m < 2; ++m) {
            curH[m] = *(const bf16x8*)(a2Ptr[m]);
            midH[m] = *(const bf16x8*)(a2Ptr[m] + 512);
        }
    }

    const int nchunks = KT / 8;
    for (int kc = 0; kc < nchunks; ++kc) {
        // ---- fill B-hi LDS for this 8-ktile chunk (2048 uint4, 512 thr) ----
        {
            const uint4* gh = (const uint4*)Bh + sliceBase;
            uint4* lh = (uint4*)Bs;
#pragma unroll
            for (int i = 0; i < 4; ++i) {
                int u = i * 512 + tid;
                int nt = u >> 9;
                int ktl = (u & 511) >> 6, j = u & 63;
                lh[u] = gh[((size_t)nt * KT + kc * 8 + ktl) * 64 + j];
            }
        }
        __syncthreads();

#pragma unroll
        for (int ktl = 0; ktl < 8; ++ktl) {
            const int kt = kc * 8 + ktl;
            // ---- prefetch (MODE0: kt+1; MODE1: kt+2) ----
            float4 nxtA[2][2];
            bf16x8 nxtH[2];
            const bool hn1 = (kt + 1 < KT), hn2 = (kt + 2 < KT);
            if (MODE == 0) {
                if (hn1) {
#pragma unroll
                    for (int m = 0; m < 2; ++m) {
                        nxtA[m][0] = *(const float4*)(aPtr[m] + (size_t)(kt + 1) * 32);
                        nxtA[m][1] = *(const float4*)(aPtr[m] + (size_t)(kt + 1) * 32 + 4);
                    }
                }
            } else {
                if (hn2) {
#pragma unroll
                    for (int m = 0; m < 2; ++m)
                        nxtH[m] = *(const bf16x8*)(a2Ptr[m] + (size_t)(kt + 2) * 512);
                }
            }
            // ---- current fragments ----
            bf16x8 ah[2], al[2];
            if (MODE == 0) {
#pragma unroll
                for (int m = 0; m < 2; ++m)
                    cvt_split(curA[m][0], curA[m][1], ah[m], al[m]);
            } else {
#pragma unroll
                for (int m = 0; m < 2; ++m) ah[m] = curH[m];
            }
            // ---- MFMA cluster ----
#pragma unroll
            for (int n = 0; n < 4; ++n) {
                bf16x8 bh = *(const bf16x8*)&Bs[(n * 8 + ktl) * 512 + lane * 8];
#pragma unroll
                for (int m = 0; m < 2; ++m) {
                    acc[m][n] = __builtin_amdgcn_mfma_f32_16x16x32_bf16(
                        ah[m], bh, acc[m][n], 0, 0, 0);
                    if (MODE == 0)
                        acc[m][n] = __builtin_amdgcn_mfma_f32_16x16x32_bf16(
                            al[m], bh, acc[m][n], 0, 0, 0);
                }
            }
            // ---- rotate ----
            if (MODE == 0) {
                if (hn1) {
#pragma unroll
                    for (int m = 0; m < 2; ++m) {
                        curA[m][0] = nxtA[m][0];
                        curA[m][1] = nxtA[m][1];
                    }
                }
            } else {
#pragma unroll
                for (int m = 0; m < 2; ++m) {
                    curH[m] = midH[m];
                    if (hn2) midH[m] = nxtH[m];
                }
            }
        }
        __syncthreads();
    }
    // ---- epilogue: C/D col=lane&15, row=(lane>>4)*4+reg (verified r4-r14); bf16 out ----
#pragma unroll
    for (int n = 0; n < 4; ++n) {
        int gcol = slice * 64 + n * 16 + r15;
        float bv = (gcol < 256) ? bL[gcol] : bR[gcol - 256];
#pragma unroll
        for (int m = 0; m < 2; ++m) {
#pragma unroll
            for (int r = 0; r < 4; ++r) {
                int grow = m0 + w * 32 + m * 16 + kq * 4 + r;
                if (grow < M)
                    C[(size_t)grow * 512 + gcol] = f2bf(acc[m][n][r] + bv);
            }
        }
    }
}

// ================= CSR build over dst (verified r5-r14) =================
__global__ void csr_count(const int* __restrict__ ei, int* __restrict__ cnt) {
    int e = blockIdx.x * 256 + threadIdx.x;
    if (e < NE) atomicAdd(&cnt[ei[NE + e]], 1);
}
__launch_bounds__(1024)
__global__ void csr_offsets(const int* __restrict__ cnt, int* __restrict__ off,
                            int* __restrict__ cursor) {
    __shared__ int s[1024];
    const int t = threadIdx.x;
    const int PER = 49;
    const int base = t * PER;
    int sum = 0;
    for (int i = 0; i < PER; ++i) {
        int idx = base + i;
        if (idx < NN) sum += cnt[idx];
    }
    s[t] = sum;
    __syncthreads();
    for (int d = 1; d < 1024; d <<= 1) {
        int v = (t >= d) ? s[t - d] : 0;
        __syncthreads();
        s[t] += v;
        __syncthreads();
    }
    int run = s[t] - sum;
    for (int i = 0; i < PER; ++i) {
        int idx = base + i;
        if (idx < NN) {
            off[idx] = run;
            cursor[idx] = run;
            run += cnt[idx];
            if (idx == NN - 1) off[NN] = run;
        }
    }
}
__global__ void csr_fill(const int* __restrict__ ei, int* __restrict__ cursor,
                         int* __restrict__ eidl) {
    int e = blockIdx.x * 256 + threadIdx.x;
    if (e < NE) {
        int d = ei[NE + e];
        int p = atomicAdd(&cursor[d], 1);
        eidl[p] = e;
    }
}

// ---------- per-edge logit partial (verbatim r6) ----------
__device__ __forceinline__ float edge_part(const float4& l, const float4& r,
                                           const float* ev, const float (*rW)[4],
                                           const float4& attv) {
    const float* lp = &l.x; const float* rp = &r.x; const float* ap = &attv.x;
    float part = 0.f;
#pragma unroll
    for (int j = 0; j < 4; ++j) {
        float ecf = 0.f;
#pragma unroll
        for (int d = 0; d < 12; ++d) ecf = fmaf(ev[d], rW[d][j], ecf);
        float mv = lp[j] + rp[j] + ecf;
        mv = mv > 0.f ? mv : SLOPE * mv;
        part = fmaf(mv, ap[j], part);
    }
    return part;
}

// ---------- fused node pass: bf16 gathers; OUTMODE 0 = tiled-bf16 h1, 1 = f32 compact ----------
template<int NHEADS, int OUTMODE>
__launch_bounds__(256)
__global__ void node_fused(const unsigned short* __restrict__ x16,
                           const int* __restrict__ off, const int* __restrict__ eidl,
                           const int* __restrict__ ei, const float* __restrict__ ea,
                           const float* __restrict__ We, int ldwe,
                           const float* __restrict__ att,
                           const float* __restrict__ bias, const float* __restrict__ gam,
                           const float* __restrict__ bet, const float* __restrict__ mu,
                           const float* __restrict__ var,
                           unsigned short* __restrict__ h1t, int hcol,
                           float* __restrict__ fout) {
    const int n = blockIdx.x * 4 + (threadIdx.x >> 6);
    const int lane = threadIdx.x & 63;
    const int cf = lane * 4;
    float rW[12][4];
#pragma unroll
    for (int d = 0; d < 12; ++d) {
        float4 w = *(const float4*)&We[(size_t)d * ldwe + cf];
        rW[d][0] = w.x; rW[d][1] = w.y; rW[d][2] = w.z; rW[d][3] = w.w;
    }
    const float4 attv = *(const float4*)&att[cf];
    float4 xr4;
    {
        ushort4 u = *(const ushort4*)(x16 + (size_t)n * 512 + 256 + cf);
        xr4 = make_float4(bf2f(u.x), bf2f(u.y), bf2f(u.z), bf2f(u.w));
    }
    float acc[4] = {0.f, 0.f, 0.f, 0.f};
    float den = 0.f;
    const int beg = off[n], end = off[n + 1];
    constexpr int RED = 64 / NHEADS;
    int k = beg;
    for (; k + 2 <= end; k += 2) {
        int e0 = eidl[k], e1 = eidl[k + 1];
        int s0 = ei[e0], s1 = ei[e1];
        float ev0[12], ev1[12];
        const float2* p0 = (const float2*)(ea + (size_t)e0 * 12);
        const float2* p1 = (const float2*)(ea + (size_t)e1 * 12);
#pragma unroll
        for (int d = 0; d < 6; ++d) {
            float2 a = p0[d], b = p1[d];
            ev0[2 * d] = a.x; ev0[2 * d + 1] = a.y;
            ev1[2 * d] = b.x; ev1[2 * d + 1] = b.y;
        }
        ushort4 u0 = *(const ushort4*)(x16 + (size_t)s0 * 512 + cf);
        ushort4 u1 = *(const ushort4*)(x16 + (size_t)s1 * 512 + cf);
        float4 l0 = make_float4(bf2f(u0.x), bf2f(u0.y), bf2f(u0.z), bf2f(u0.w));
        float4 l1 = make_float4(bf2f(u1.x), bf2f(u1.y), bf2f(u1.z), bf2f(u1.w));
        float pa = edge_part(l0, xr4, ev0, rW, attv);
        float pb = edge_part(l1, xr4, ev1, rW, attv);
#pragma unroll
        for (int o = RED / 2; o > 0; o >>= 1) {
            pa += __shfl_xor(pa, o);
            pb += __shfl_xor(pb, o);
        }
        float ex0 = __expf(pa), ex1 = __expf(pb);
        den += ex0 + ex1;
        const float* lp0 = &l0.x; const float* lp1 = &l1.x;
#pragma unroll
        for (int j = 0; j < 4; ++j)
            acc[j] = fmaf(ex0, lp0[j], fmaf(ex1, lp1[j], acc[j]));
    }
    if (k < end) {
        int e0 = eidl[k];
        int s0 = ei[e0];
        float ev0[12];
        const float2* p0 = (const float2*)(ea + (size_t)e0 * 12);
#pragma unroll
        for (int d = 0; d < 6; ++d) {
            float2 a = p0[d];
            ev0[2 * d] = a.x; ev0[2 * d + 1] = a.y;
        }
        ushort4 u0 = *(const ushort4*)(x16 + (size_t)s0 * 512 + cf);
        float4 l0 = make_float4(bf2f(u0.x), bf2f(u0.y), bf2f(u0.z), bf2f(u0.w));
        float pa = edge_part(l0, xr4, ev0, rW, attv);
#pragma unroll
        for (int o = RED / 2; o > 0; o >>= 1) pa += __shfl_xor(pa, o);
        float ex0 = __expf(pa);
        den += ex0;
        const float* lp0 = &l0.x;
#pragma unroll
        for (int j = 0; j < 4; ++j) acc[j] = fmaf(ex0, lp0[j], acc[j]);
    }
    const float inv = 1.f / (den + 1e-16f);
    float o[4];
#pragma unroll
    for (int j = 0; j < 4; ++j) {
        int c = cf + j;
        float t = fmaxf(acc[j] * inv + bias[c], 0.f);
        o[j] = (t - mu[c]) * rsqrtf(var[c] + EPSBN) * gam[c] + bet[c];
    }
    if (OUTMODE == 0) {
        // fragment-tiled bf16 write: element (row=n, k=hcol+cf+j)
        ushort4 hv;
        hv.x = f2bf(o[0]); hv.y = f2bf(o[1]); hv.z = f2bf(o[2]); hv.w = f2bf(o[3]);
        const int kt = (hcol >> 5) + (cf >> 5);
        size_t idx = (size_t)(n >> 4) * 16384 + (size_t)kt * 512
                   + ((((cf >> 3) & 3) << 4) + (n & 15)) * 8 + (cf & 7);
        *(ushort4*)(h1t + idx) = hv;
    } else {
        *(float4*)(fout + (size_t)n * 256 + cf) = make_float4(o[0], o[1], o[2], o[3]);
    }
}

// ================= head MLP (h2 compact f32 [NN][256]) =================
__launch_bounds__(64)
__global__ void head_mlp(const float* __restrict__ h2, const int* __restrict__ n_nodes,
                         const float* __restrict__ Wf1, const float* __restrict__ bf1,
                         const float* __restrict__ Wf2, const float* __restrict__ bf2,
                         float* __restrict__ out) {
    const int g = blockIdx.x;
    const int t = threadIdx.x;
    int acc = 0;
    for (int i = t; i <= g; i += 64) acc += n_nodes[i];
#pragma unroll
    for (int off = 32; off > 0; off >>= 1) acc += __shfl_xor(acc, off);
    const int node = acc - 1;
    __shared__ float row[256];
    for (int i = t; i < 256; i += 64) row[i] = h2[(size_t)node * 256 + i];
    __syncthreads();
    float hid = bf1[t];
    for (int k = 0; k < 256; ++k) hid = fmaf(row[k], Wf1[k * 64 + t], hid);
    hid = fmaxf(hid, 0.f);
    float p = hid * Wf2[t];
#pragma unroll
    for (int off = 32; off > 0; off >>= 1) p += __shfl_xor(p, off);
    if (t == 0) out[g] = p + bf2[0];
}

extern "C" void kernel_launch(void* const* d_in, const int* in_sizes, int n_in,
                              void* d_out, int out_size, void* d_ws, size_t ws_size,
                              hipStream_t stream) {
    const float* x   = (const float*)d_in[0];
    const int*   ei  = (const int*)d_in[1];
    const float* ea  = (const float*)d_in[2];
    const int*   nnd = (const int*)d_in[3];
    const float* Wl1 = (const float*)d_in[4];
    const float* bl1 = (const float*)d_in[5];
    const float* Wr1 = (const float*)d_in[6];
    const float* br1 = (const float*)d_in[7];
    const float* We1 = (const float*)d_in[8];
    const float* att1= (const float*)d_in[9];
    const float* b1  = (const float*)d_in[10];
    const float* g1  = (const float*)d_in[11];
    const float* be1 = (const float*)d_in[12];
    const float* m1  = (const float*)d_in[13];
    const float* v1  = (const float*)d_in[14];
    const float* Wl2 = (const float*)d_in[15];
    const float* bl2 = (const float*)d_in[16];
    const float* Wr2 = (const float*)d_in[17];
    const float* br2 = (const float*)d_in[18];
    const float* We2 = (const float*)d_in[19];
    const float* att2= (const float*)d_in[20];
    const float* b2  = (const float*)d_in[21];
    const float* g2  = (const float*)d_in[22];
    const float* be2 = (const float*)d_in[23];
    const float* m2  = (const float*)d_in[24];
    const float* v2  = (const float*)d_in[25];
    const float* Wf1 = (const float*)d_in[26];
    const float* bf1 = (const float*)d_in[27];
    const float* Wf2 = (const float*)d_in[28];
    const float* bf2 = (const float*)d_in[29];
    float* out = (float*)d_out;

    // ---- workspace (~157 MB; proven >= 212.8 MB available) ----
    const size_t XB = (size_t)NN * 512 * 2;        // 51.2 MB bf16 panel (xlr / xlr2)
    const size_t HB = (size_t)3136 * 16384 * 2;    // 102.8 MB h1 tiled bf16 (3136 tiles)
    const size_t WPB = (size_t)524288 * 2;         // 1 MB per weight plane
    char* ws = (char*)d_ws;
    size_t off = 0;
    unsigned short* panel = (unsigned short*)(ws + off); off += XB;   // xlr(L1) / xlr2(L2)
    unsigned short* h1t   = (unsigned short*)(ws + off);              // tiled h1...
    float*          h2f   = (float*)(ws + off);    off += HB;         // ...then compact f32 h2
    unsigned short* B1h = (unsigned short*)(ws + off); off += WPB;
    unsigned short* B2h = (unsigned short*)(ws + off); off += WPB;
    int* cnt    = (int*)(ws + off); off += (size_t)NN * 4;
    int* csroff = (int*)(ws + off); off += ((size_t)(NN + 1) * 4 + 15) & ~15ull;
    int* cursor = (int*)(ws + off); off += (size_t)NN * 4;
    int* eidl   = (int*)(ws + off); off += (size_t)NE * 4;
    if (ws_size < off) {
        fill_val<<<(out_size + 255) / 256, 256, 0, stream>>>(out, out_size, 1e30f);
        return;
    }

    // ---- CSR build (once) ----
    hipMemsetAsync(cnt, 0, (size_t)NN * 4, stream);
    csr_count<<<(NE + 255) / 256, 256, 0, stream>>>(ei, cnt);
    csr_offsets<<<1, 1024, 0, stream>>>(cnt, csroff, cursor);
    csr_fill<<<(NE + 255) / 256, 256, 0, stream>>>(ei, cursor, eidl);

    // ---- weight prep ----
    wprep1t<<<2048, 256, 0, stream>>>(Wl1, Wr1, B1h);
    wprep2t<<<2048, 256, 0, stream>>>(Wl2, Wr2, B2h);

    // strip-clustered 1D grid: 196 strips of 256 rows -> pad to 200 (25 groups of 8)
    const int gemmBlocks = 25 * 64;   // 1600
    const int nodeBlocks = NN / 4;

    // ================= layer 1, per head =================
    for (int h = 0; h < NH; ++h) {
        gemm_bs<0><<<gemmBlocks, 512, 0, stream>>>(
            x, nullptr, B1h + (size_t)h * 131072, 8,
            bl1 + h * 256, br1 + h * 256, panel, NN);
        node_fused<1, 0><<<nodeBlocks, 256, 0, stream>>>(
            panel, csroff, eidl, ei, ea, We1 + h * 256, 1024, att1 + h * 256,
            b1 + h * 256, g1 + h * 256, be1 + h * 256, m1 + h * 256, v1 + h * 256,
            h1t, h * 256, nullptr);
    }

    // ================= layer 2: single K=1024 GEMM (tiled A, bf16 C) =================
    gemm_bs<1><<<gemmBlocks, 512, 0, stream>>>(
        nullptr, h1t, B2h, 32, bl2, br2, panel, NN);
    node_fused<4, 1><<<nodeBlocks, 256, 0, stream>>>(
        panel, csroff, eidl, ei, ea, We2, 256, att2, b2, g2, be2, m2, v2,
        nullptr, 0, h2f);

    head_mlp<<<NG, 64, 0, stream>>>(h2f, nnd, Wf1, bf1, Wf2, bf2, out);
}

// Round 16
// 830.536 us; speedup vs baseline: 1.5100x; 1.1431x over previous
//
#include <hip/hip_runtime.h>
#include <math.h>

#define NN 50000
#define NE 200000
#define NH 4
#define NG 100
#define EPSBN 1e-5f
#define SLOPE 0.2f

typedef __attribute__((ext_vector_type(8))) short bf16x8;
typedef __attribute__((ext_vector_type(4))) float f32x4;

union U8 { bf16x8 v; uint4 q; unsigned w[4]; };

__device__ __forceinline__ unsigned short f2bf(float f) {
    unsigned u = __float_as_uint(f);
    unsigned r = (u + 0x7fffu + ((u >> 16) & 1u)) >> 16;   // RNE
    return (unsigned short)r;
}
__device__ __forceinline__ float bf2f(unsigned short s) {
    return __uint_as_float(((unsigned)s) << 16);
}

__global__ void fill_val(float* p, int n, float v) {
    int i = blockIdx.x * 256 + threadIdx.x;
    if (i < n) p[i] = v;
}

// ================= weight prep (verbatim r15) =================
__global__ void wprep1t(const float* __restrict__ Wl, const float* __restrict__ Wr,
                        unsigned short* __restrict__ Bh) {
    int idx = blockIdx.x * 256 + threadIdx.x;   // 524288
    int n = idx & 511, k = (idx >> 9) & 255, h = idx >> 17;
    const float* W = (n < 256) ? Wl : Wr;
    float w = W[(size_t)k * 1024 + h * 256 + (n & 255)];
    size_t dst = (size_t)h * 131072 + (((size_t)(n >> 4) * 8 + (k >> 5)) << 9)
               + ((((k >> 3) & 3) << 4) + (n & 15)) * 8 + (k & 7);
    Bh[dst] = f2bf(w);
}
__global__ void wprep2t(const float* __restrict__ Wl, const float* __restrict__ Wr,
                        unsigned short* __restrict__ Bh) {
    int idx = blockIdx.x * 256 + threadIdx.x;   // 524288
    int n = idx >> 10, k = idx & 1023;
    const float* W = (n < 256) ? Wl : Wr;
    float w = W[(size_t)k * 256 + (n & 255)];
    size_t dst = (((size_t)(n >> 4) * 32 + (k >> 5)) << 9)
               + ((((k >> 3) & 3) << 4) + (n & 15)) * 8 + (k & 7);
    Bh[dst] = f2bf(w);
}

__device__ __forceinline__ void cvt_split(const float4& v0, const float4& v1,
                                          bf16x8& h, bf16x8& l) {
    float vv[8];
    *(float4*)&vv[0] = v0; *(float4*)&vv[4] = v1;
    U8 uh, ul;
#pragma unroll
    for (int j = 0; j < 4; ++j) {
        float a0 = vv[2 * j], a1 = vv[2 * j + 1];
        unsigned u0 = __float_as_uint(a0), u1 = __float_as_uint(a1);
        uh.w[j] = (u0 >> 16) | (u1 & 0xFFFF0000u);             // trunc hi pair
        float l0 = a0 - __uint_as_float(u0 & 0xFFFF0000u);
        float l1 = a1 - __uint_as_float(u1 & 0xFFFF0000u);
        ul.w[j] = (unsigned)f2bf(l0) | ((unsigned)f2bf(l1) << 16);
    }
    h = uh.v; l = ul.v;
}

// ================= MFMA GEMM (verbatim r15) =================
template<int MODE>
__launch_bounds__(512, 4)
__global__ void gemm_bs(const float* __restrict__ Af,
                        const unsigned short* __restrict__ Atile,
                        const unsigned short* __restrict__ Bh, int KT,
                        const float* __restrict__ bL, const float* __restrict__ bR,
                        unsigned short* __restrict__ C, int M) {
    __shared__ unsigned short Bs[16384];      // 32 KB: [4nt][8kt][512]
    const int p = blockIdx.x;
    const int strip = ((p >> 6) << 3) + (p & 7);
    if (strip * 256 >= M) return;             // padded tail
    const int slice = (p >> 3) & 7;
    const int m0 = strip * 256;
    const int tid = threadIdx.x;
    const int lane = tid & 63, w = tid >> 6;
    const int r15 = lane & 15, kq = lane >> 4;
    const size_t sliceBase = (size_t)slice * 4 * KT * 64;   // uint4 units

    f32x4 acc[2][4];
#pragma unroll
    for (int m = 0; m < 2; ++m)
#pragma unroll
        for (int n = 0; n < 4; ++n) acc[m][n] = (f32x4){0.f, 0.f, 0.f, 0.f};

    const float* aPtr[2];
    const unsigned short* a2Ptr[2];
#pragma unroll
    for (int m = 0; m < 2; ++m) {
        if (MODE == 0) {
            int row = m0 + w * 32 + m * 16 + r15;
            row = row < M ? row : M - 1;
            aPtr[m] = Af + (size_t)row * 256 + kq * 8;
        } else {
            a2Ptr[m] = Atile + (size_t)(strip * 16 + w * 2 + m) * 16384 + lane * 8;
        }
    }

    // ---- prime A pipeline ----
    float4 curA[2][2];
    bf16x8 curH[2], midH[2];
    if (MODE == 0) {
#pragma unroll
        for (int m = 0; m < 2; ++m) {
            curA[m][0] = *(const float4*)(aPtr[m]);
            curA[m][1] = *(const float4*)(aPtr[m] + 4);
        }
    } else {
#pragma unroll
        for (int m = 0; m < 2; ++m) {
            curH[m] = *(const bf16x8*)(a2Ptr[m]);
            midH[m] = *(const bf16x8*)(a2Ptr[m] + 512);
        }
    }

    const int nchunks = KT / 8;
    for (int kc = 0; kc < nchunks; ++kc) {
        {
            const uint4* gh = (const uint4*)Bh + sliceBase;
            uint4* lh = (uint4*)Bs;
#pragma unroll
            for (int i = 0; i < 4; ++i) {
                int u = i * 512 + tid;
                int nt = u >> 9;
                int ktl = (u & 511) >> 6, j = u & 63;
                lh[u] = gh[((size_t)nt * KT + kc * 8 + ktl) * 64 + j];
            }
        }
        __syncthreads();

#pragma unroll
        for (int ktl = 0; ktl < 8; ++ktl) {
            const int kt = kc * 8 + ktl;
            float4 nxtA[2][2];
            bf16x8 nxtH[2];
            const bool hn1 = (kt + 1 < KT), hn2 = (kt + 2 < KT);
            if (MODE == 0) {
                if (hn1) {
#pragma unroll
                    for (int m = 0; m < 2; ++m) {
                        nxtA[m][0] = *(const float4*)(aPtr[m] + (size_t)(kt + 1) * 32);
                        nxtA[m][1] = *(const float4*)(aPtr[m] + (size_t)(kt + 1) * 32 + 4);
                    }
                }
            } else {
                if (hn2) {
#pragma unroll
                    for (int m = 0; m < 2; ++m)
                        nxtH[m] = *(const bf16x8*)(a2Ptr[m] + (size_t)(kt + 2) * 512);
                }
            }
            bf16x8 ah[2], al[2];
            if (MODE == 0) {
#pragma unroll
                for (int m = 0; m < 2; ++m)
                    cvt_split(curA[m][0], curA[m][1], ah[m], al[m]);
            } else {
#pragma unroll
                for (int m = 0; m < 2; ++m) ah[m] = curH[m];
            }
#pragma unroll
            for (int n = 0; n < 4; ++n) {
                bf16x8 bh = *(const bf16x8*)&Bs[(n * 8 + ktl) * 512 + lane * 8];
#pragma unroll
                for (int m = 0; m < 2; ++m) {
                    acc[m][n] = __builtin_amdgcn_mfma_f32_16x16x32_bf16(
                        ah[m], bh, acc[m][n], 0, 0, 0);
                    if (MODE == 0)
                        acc[m][n] = __builtin_amdgcn_mfma_f32_16x16x32_bf16(
                            al[m], bh, acc[m][n], 0, 0, 0);
                }
            }
            if (MODE == 0) {
                if (hn1) {
#pragma unroll
                    for (int m = 0; m < 2; ++m) {
                        curA[m][0] = nxtA[m][0];
                        curA[m][1] = nxtA[m][1];
                    }
                }
            } else {
#pragma unroll
                for (int m = 0; m < 2; ++m) {
                    curH[m] = midH[m];
                    if (hn2) midH[m] = nxtH[m];
                }
            }
        }
        __syncthreads();
    }
#pragma unroll
    for (int n = 0; n < 4; ++n) {
        int gcol = slice * 64 + n * 16 + r15;
        float bv = (gcol < 256) ? bL[gcol] : bR[gcol - 256];
#pragma unroll
        for (int m = 0; m < 2; ++m) {
#pragma unroll
            for (int r = 0; r < 4; ++r) {
                int grow = m0 + w * 32 + m * 16 + kq * 4 + r;
                if (grow < M)
                    C[(size_t)grow * 512 + gcol] = f2bf(acc[m][n][r] + bv);
            }
        }
    }
}

// ================= CSR build: parallel 3-phase scan (r16) =================
#define SCAN_BLOCKS 196   // 196*256 = 50176 >= NN

__global__ void csr_count(const int* __restrict__ ei, int* __restrict__ cnt) {
    int e = blockIdx.x * 256 + threadIdx.x;
    if (e < NE) atomicAdd(&cnt[ei[NE + e]], 1);
}
// phase 1: per-block totals (tree reduce)
__global__ void csr_bsum(const int* __restrict__ cnt, int* __restrict__ bsum) {
    __shared__ int s[256];
    int idx = blockIdx.x * 256 + threadIdx.x;
    int v = idx < NN ? cnt[idx] : 0;
    s[threadIdx.x] = v;
    __syncthreads();
    for (int d = 128; d > 0; d >>= 1) {
        if (threadIdx.x < d) s[threadIdx.x] += s[threadIdx.x + d];
        __syncthreads();
    }
    if (threadIdx.x == 0) bsum[blockIdx.x] = s[0];
}
// phase 2: exclusive scan of SCAN_BLOCKS block sums (one 256-thread block)
__global__ void csr_scan_bsum(int* __restrict__ bsum) {
    __shared__ int s[256];
    int t = threadIdx.x;
    int v = t < SCAN_BLOCKS ? bsum[t] : 0;
    s[t] = v;
    __syncthreads();
    for (int d = 1; d < 256; d <<= 1) {
        int x = (t >= d) ? s[t - d] : 0;
        __syncthreads();
        s[t] += x;
        __syncthreads();
    }
    if (t < SCAN_BLOCKS) bsum[t] = s[t] - v;   // exclusive
}
// phase 3: per-block inclusive scan + base -> offsets
__global__ void csr_apply(const int* __restrict__ cnt, const int* __restrict__ bsum,
                          int* __restrict__ off, int* __restrict__ cursor) {
    __shared__ int s[256];
    int idx = blockIdx.x * 256 + threadIdx.x;
    int v = (idx < NN) ? cnt[idx] : 0;
    s[threadIdx.x] = v;
    __syncthreads();
    for (int d = 1; d < 256; d <<= 1) {
        int x = (threadIdx.x >= d) ? s[threadIdx.x - d] : 0;
        __syncthreads();
        s[threadIdx.x] += x;
        __syncthreads();
    }
    int o = bsum[blockIdx.x] + s[threadIdx.x] - v;   // exclusive prefix
    if (idx < NN) { off[idx] = o; cursor[idx] = o; }
    if (idx == NN - 1) off[NN] = o + v;
}
__global__ void csr_fill(const int* __restrict__ ei, int* __restrict__ cursor,
                         int* __restrict__ eidl) {
    int e = blockIdx.x * 256 + threadIdx.x;
    if (e < NE) {
        int d = ei[NE + e];
        int p = atomicAdd(&cursor[d], 1);
        eidl[p] = e;
    }
}

// ---------- per-edge logit partial (verbatim r6) ----------
__device__ __forceinline__ float edge_part(const float4& l, const float4& r,
                                           const float* ev, const float (*rW)[4],
                                           const float4& attv) {
    const float* lp = &l.x; const float* rp = &r.x; const float* ap = &attv.x;
    float part = 0.f;
#pragma unroll
    for (int j = 0; j < 4; ++j) {
        float ecf = 0.f;
#pragma unroll
        for (int d = 0; d < 12; ++d) ecf = fmaf(ev[d], rW[d][j], ecf);
        float mv = lp[j] + rp[j] + ecf;
        mv = mv > 0.f ? mv : SLOPE * mv;
        part = fmaf(mv, ap[j], part);
    }
    return part;
}

// ---------- fused node pass (verbatim r15) ----------
template<int NHEADS, int OUTMODE>
__launch_bounds__(256)
__global__ void node_fused(const unsigned short* __restrict__ x16,
                           const int* __restrict__ off, const int* __restrict__ eidl,
                           const int* __restrict__ ei, const float* __restrict__ ea,
                           const float* __restrict__ We, int ldwe,
                           const float* __restrict__ att,
                           const float* __restrict__ bias, const float* __restrict__ gam,
                           const float* __restrict__ bet, const float* __restrict__ mu,
                           const float* __restrict__ var,
                           unsigned short* __restrict__ h1t, int hcol,
                           float* __restrict__ fout) {
    const int n = blockIdx.x * 4 + (threadIdx.x >> 6);
    const int lane = threadIdx.x & 63;
    const int cf = lane * 4;
    float rW[12][4];
#pragma unroll
    for (int d = 0; d < 12; ++d) {
        float4 w = *(const float4*)&We[(size_t)d * ldwe + cf];
        rW[d][0] = w.x; rW[d][1] = w.y; rW[d][2] = w.z; rW[d][3] = w.w;
    }
    const float4 attv = *(const float4*)&att[cf];
    float4 xr4;
    {
        ushort4 u = *(const ushort4*)(x16 + (size_t)n * 512 + 256 + cf);
        xr4 = make_float4(bf2f(u.x), bf2f(u.y), bf2f(u.z), bf2f(u.w));
    }
    float acc[4] = {0.f, 0.f, 0.f, 0.f};
    float den = 0.f;
    const int beg = off[n], end = off[n + 1];
    constexpr int RED = 64 / NHEADS;
    int k = beg;
    for (; k + 2 <= end; k += 2) {
        int e0 = eidl[k], e1 = eidl[k + 1];
        int s0 = ei[e0], s1 = ei[e1];
        float ev0[12], ev1[12];
        const float2* p0 = (const float2*)(ea + (size_t)e0 * 12);
        const float2* p1 = (const float2*)(ea + (size_t)e1 * 12);
#pragma unroll
        for (int d = 0; d < 6; ++d) {
            float2 a = p0[d], b = p1[d];
            ev0[2 * d] = a.x; ev0[2 * d + 1] = a.y;
            ev1[2 * d] = b.x; ev1[2 * d + 1] = b.y;
        }
        ushort4 u0 = *(const ushort4*)(x16 + (size_t)s0 * 512 + cf);
        ushort4 u1 = *(const ushort4*)(x16 + (size_t)s1 * 512 + cf);
        float4 l0 = make_float4(bf2f(u0.x), bf2f(u0.y), bf2f(u0.z), bf2f(u0.w));
        float4 l1 = make_float4(bf2f(u1.x), bf2f(u1.y), bf2f(u1.z), bf2f(u1.w));
        float pa = edge_part(l0, xr4, ev0, rW, attv);
        float pb = edge_part(l1, xr4, ev1, rW, attv);
#pragma unroll
        for (int o = RED / 2; o > 0; o >>= 1) {
            pa += __shfl_xor(pa, o);
            pb += __shfl_xor(pb, o);
        }
        float ex0 = __expf(pa), ex1 = __expf(pb);
        den += ex0 + ex1;
        const float* lp0 = &l0.x; const float* lp1 = &l1.x;
#pragma unroll
        for (int j = 0; j < 4; ++j)
            acc[j] = fmaf(ex0, lp0[j], fmaf(ex1, lp1[j], acc[j]));
    }
    if (k < end) {
        int e0 = eidl[k];
        int s0 = ei[e0];
        float ev0[12];
        const float2* p0 = (const float2*)(ea + (size_t)e0 * 12);
#pragma unroll
        for (int d = 0; d < 6; ++d) {
            float2 a = p0[d];
            ev0[2 * d] = a.x; ev0[2 * d + 1] = a.y;
        }
        ushort4 u0 = *(const ushort4*)(x16 + (size_t)s0 * 512 + cf);
        float4 l0 = make_float4(bf2f(u0.x), bf2f(u0.y), bf2f(u0.z), bf2f(u0.w));
        float pa = edge_part(l0, xr4, ev0, rW, attv);
#pragma unroll
        for (int o = RED / 2; o > 0; o >>= 1) pa += __shfl_xor(pa, o);
        float ex0 = __expf(pa);
        den += ex0;
        const float* lp0 = &l0.x;
#pragma unroll
        for (int j = 0; j < 4; ++j) acc[j] = fmaf(ex0, lp0[j], acc[j]);
    }
    const float inv = 1.f / (den + 1e-16f);
    float o[4];
#pragma unroll
    for (int j = 0; j < 4; ++j) {
        int c = cf + j;
        float t = fmaxf(acc[j] * inv + bias[c], 0.f);
        o[j] = (t - mu[c]) * rsqrtf(var[c] + EPSBN) * gam[c] + bet[c];
    }
    if (OUTMODE == 0) {
        ushort4 hv;
        hv.x = f2bf(o[0]); hv.y = f2bf(o[1]); hv.z = f2bf(o[2]); hv.w = f2bf(o[3]);
        const int kt = (hcol >> 5) + (cf >> 5);
        size_t idx = (size_t)(n >> 4) * 16384 + (size_t)kt * 512
                   + ((((cf >> 3) & 3) << 4) + (n & 15)) * 8 + (cf & 7);
        *(ushort4*)(h1t + idx) = hv;
    } else {
        *(float4*)(fout + (size_t)n * 256 + cf) = make_float4(o[0], o[1], o[2], o[3]);
    }
}

// ================= head MLP (verbatim r15) =================
__launch_bounds__(64)
__global__ void head_mlp(const float* __restrict__ h2, const int* __restrict__ n_nodes,
                         const float* __restrict__ Wf1, const float* __restrict__ bf1,
                         const float* __restrict__ Wf2, const float* __restrict__ bf2,
                         float* __restrict__ out) {
    const int g = blockIdx.x;
    const int t = threadIdx.x;
    int acc = 0;
    for (int i = t; i <= g; i += 64) acc += n_nodes[i];
#pragma unroll
    for (int off = 32; off > 0; off >>= 1) acc += __shfl_xor(acc, off);
    const int node = acc - 1;
    __shared__ float row[256];
    for (int i = t; i < 256; i += 64) row[i] = h2[(size_t)node * 256 + i];
    __syncthreads();
    float hid = bf1[t];
    for (int k = 0; k < 256; ++k) hid = fmaf(row[k], Wf1[k * 64 + t], hid);
    hid = fmaxf(hid, 0.f);
    float p = hid * Wf2[t];
#pragma unroll
    for (int off = 32; off > 0; off >>= 1) p += __shfl_xor(p, off);
    if (t == 0) out[g] = p + bf2[0];
}

extern "C" void kernel_launch(void* const* d_in, const int* in_sizes, int n_in,
                              void* d_out, int out_size, void* d_ws, size_t ws_size,
                              hipStream_t stream) {
    const float* x   = (const float*)d_in[0];
    const int*   ei  = (const int*)d_in[1];
    const float* ea  = (const float*)d_in[2];
    const int*   nnd = (const int*)d_in[3];
    const float* Wl1 = (const float*)d_in[4];
    const float* bl1 = (const float*)d_in[5];
    const float* Wr1 = (const float*)d_in[6];
    const float* br1 = (const float*)d_in[7];
    const float* We1 = (const float*)d_in[8];
    const float* att1= (const float*)d_in[9];
    const float* b1  = (const float*)d_in[10];
    const float* g1  = (const float*)d_in[11];
    const float* be1 = (const float*)d_in[12];
    const float* m1  = (const float*)d_in[13];
    const float* v1  = (const float*)d_in[14];
    const float* Wl2 = (const float*)d_in[15];
    const float* bl2 = (const float*)d_in[16];
    const float* Wr2 = (const float*)d_in[17];
    const float* br2 = (const float*)d_in[18];
    const float* We2 = (const float*)d_in[19];
    const float* att2= (const float*)d_in[20];
    const float* b2  = (const float*)d_in[21];
    const float* g2  = (const float*)d_in[22];
    const float* be2 = (const float*)d_in[23];
    const float* m2  = (const float*)d_in[24];
    const float* v2  = (const float*)d_in[25];
    const float* Wf1 = (const float*)d_in[26];
    const float* bf1 = (const float*)d_in[27];
    const float* Wf2 = (const float*)d_in[28];
    const float* bf2 = (const float*)d_in[29];
    float* out = (float*)d_out;

    // ---- workspace (~157 MB; proven fit) ----
    const size_t XB = (size_t)NN * 512 * 2;        // 51.2 MB bf16 panel (xlr / xlr2)
    const size_t HB = (size_t)3136 * 16384 * 2;    // 102.8 MB h1 tiled bf16 / h2 f32
    const size_t WPB = (size_t)524288 * 2;         // 1 MB per weight plane
    char* ws = (char*)d_ws;
    size_t off = 0;
    unsigned short* panel = (unsigned short*)(ws + off); off += XB;
    unsigned short* h1t   = (unsigned short*)(ws + off);
    float*          h2f   = (float*)(ws + off);    off += HB;
    unsigned short* B1h = (unsigned short*)(ws + off); off += WPB;
    unsigned short* B2h = (unsigned short*)(ws + off); off += WPB;
    int* cnt    = (int*)(ws + off); off += (size_t)NN * 4;
    int* csroff = (int*)(ws + off); off += ((size_t)(NN + 1) * 4 + 15) & ~15ull;
    int* cursor = (int*)(ws + off); off += (size_t)NN * 4;
    int* eidl   = (int*)(ws + off); off += (size_t)NE * 4;
    int* bsum   = (int*)(ws + off); off += ((size_t)SCAN_BLOCKS * 4 + 15) & ~15ull;
    if (ws_size < off) {
        fill_val<<<(out_size + 255) / 256, 256, 0, stream>>>(out, out_size, 1e30f);
        return;
    }

    // ---- CSR build (parallel 3-phase scan; integer-exact, same CSR as r15) ----
    hipMemsetAsync(cnt, 0, (size_t)NN * 4, stream);
    csr_count<<<(NE + 255) / 256, 256, 0, stream>>>(ei, cnt);
    csr_bsum<<<SCAN_BLOCKS, 256, 0, stream>>>(cnt, bsum);
    csr_scan_bsum<<<1, 256, 0, stream>>>(bsum);
    csr_apply<<<SCAN_BLOCKS, 256, 0, stream>>>(cnt, bsum, csroff, cursor);
    csr_fill<<<(NE + 255) / 256, 256, 0, stream>>>(ei, cursor, eidl);

    // ---- weight prep ----
    wprep1t<<<2048, 256, 0, stream>>>(Wl1, Wr1, B1h);
    wprep2t<<<2048, 256, 0, stream>>>(Wl2, Wr2, B2h);

    // strip-clustered 1D grid: 196 strips of 256 rows -> pad to 200 (25 groups of 8)
    const int gemmBlocks = 25 * 64;   // 1600
    const int nodeBlocks = NN / 4;

    // ================= layer 1, per head =================
    for (int h = 0; h < NH; ++h) {
        gemm_bs<0><<<gemmBlocks, 512, 0, stream>>>(
            x, nullptr, B1h + (size_t)h * 131072, 8,
            bl1 + h * 256, br1 + h * 256, panel, NN);
        node_fused<1, 0><<<nodeBlocks, 256, 0, stream>>>(
            panel, csroff, eidl, ei, ea, We1 + h * 256, 1024, att1 + h * 256,
            b1 + h * 256, g1 + h * 256, be1 + h * 256, m1 + h * 256, v1 + h * 256,
            h1t, h * 256, nullptr);
    }

    // ================= layer 2: single K=1024 GEMM (tiled A, bf16 C) =================
    gemm_bs<1><<<gemmBlocks, 512, 0, stream>>>(
        nullptr, h1t, B2h, 32, bl2, br2, panel, NN);
    node_fused<4, 1><<<nodeBlocks, 256, 0, stream>>>(
        panel, csroff, eidl, ei, ea, We2, 256, att2, b2, g2, be2, m2, v2,
        nullptr, 0, h2f);

    head_mlp<<<NG, 64, 0, stream>>>(h2f, nnd, Wf1, bf1, Wf2, bf2, out);
}

// Round 17
// 704.020 us; speedup vs baseline: 1.7814x; 1.1797x over previous
//
#include <hip/hip_runtime.h>
#include <math.h>

#define NN 50000
#define NE 200000
#define NH 4
#define NG 100
#define EPSBN 1e-5f
#define SLOPE 0.2f
#define NROWT 3128   // 16-row tiles covering 50048 >= NN rows

typedef __attribute__((ext_vector_type(8))) short bf16x8;
typedef __attribute__((ext_vector_type(4))) float f32x4;

__device__ __forceinline__ unsigned short f2bf(float f) {
    unsigned u = __float_as_uint(f);
    unsigned r = (u + 0x7fffu + ((u >> 16) & 1u)) >> 16;   // RNE
    return (unsigned short)r;
}
__device__ __forceinline__ float bf2f(unsigned short s) {
    return __uint_as_float(((unsigned)s) << 16);
}

__global__ void fill_val(float* p, int n, float v) {
    int i = blockIdx.x * 256 + threadIdx.x;
    if (i < n) p[i] = v;
}

// ================= weight prep (verbatim r15/r16) =================
// Fragment-tiled: short idx = ((n>>4)*(K/32) + (k>>5))*512 + (((k>>3)&3)*16 + (n&15))*8 + (k&7)
__global__ void wprep1t(const float* __restrict__ Wl, const float* __restrict__ Wr,
                        unsigned short* __restrict__ Bh) {
    int idx = blockIdx.x * 256 + threadIdx.x;   // 524288
    int n = idx & 511, k = (idx >> 9) & 255, h = idx >> 17;
    const float* W = (n < 256) ? Wl : Wr;
    float w = W[(size_t)k * 1024 + h * 256 + (n & 255)];
    size_t dst = (size_t)h * 131072 + (((size_t)(n >> 4) * 8 + (k >> 5)) << 9)
               + ((((k >> 3) & 3) << 4) + (n & 15)) * 8 + (k & 7);
    Bh[dst] = f2bf(w);
}
__global__ void wprep2t(const float* __restrict__ Wl, const float* __restrict__ Wr,
                        unsigned short* __restrict__ Bh) {
    int idx = blockIdx.x * 256 + threadIdx.x;   // 524288
    int n = idx >> 10, k = idx & 1023;
    const float* W = (n < 256) ? Wl : Wr;
    float w = W[(size_t)k * 256 + (n & 255)];
    size_t dst = (((size_t)(n >> 4) * 32 + (k >> 5)) << 9)
               + ((((k >> 3) & 3) << 4) + (n & 15)) * 8 + (k & 7);
    Bh[dst] = f2bf(w);
}

// ================= x -> fragment-tiled bf16 (r17) =================
// 8 k-elems per thread; dst contiguous 8 shorts (same tiled layout, KT=8).
__global__ void xprep(const float* __restrict__ x, unsigned short* __restrict__ xt) {
    int idx = blockIdx.x * 256 + threadIdx.x;   // groups of 8; total 50048*32
    int row = idx >> 5;
    if (row >= NROWT * 16) return;
    int k8 = (idx & 31) << 3;
    unsigned short o[8];
    if (row < NN) {
        float4 v0 = *(const float4*)(x + (size_t)row * 256 + k8);
        float4 v1 = *(const float4*)(x + (size_t)row * 256 + k8 + 4);
        o[0] = f2bf(v0.x); o[1] = f2bf(v0.y); o[2] = f2bf(v0.z); o[3] = f2bf(v0.w);
        o[4] = f2bf(v1.x); o[5] = f2bf(v1.y); o[6] = f2bf(v1.z); o[7] = f2bf(v1.w);
    } else {
#pragma unroll
        for (int j = 0; j < 8; ++j) o[j] = 0;
    }
    size_t dst = (size_t)(row >> 4) * 4096 + (size_t)(k8 >> 5) * 512
               + ((((k8 >> 3) & 3) << 4) + (row & 15)) * 8;
    *(ushort4*)(xt + dst) = *(ushort4*)&o[0];
    *(ushort4*)(xt + dst + 4) = *(ushort4*)&o[4];
}

// ================= unified tiled-A single-pass MFMA GEMM (r17) =================
// C[M,512] = A@B^T + bias, A fragment-tiled bf16 (tile stride 512*KT shorts),
// B fragment-tiled bf16, K = KT*32. Block = 512 thr = 8 waves; wave w: rows
// [m0+32w,+32) (2 m-frags) x 4 n-frags (64 cols). 2-deep A prefetch; B-hi chunk
// (32 KB) in LDS. C bf16 interleaved [row][512].
// Strip-clustered grid: p -> strip=((p>>6)<<3)+(p&7), slice=(p>>3)&7.
__launch_bounds__(512, 4)
__global__ void gemm_t(const unsigned short* __restrict__ Atile,
                       const unsigned short* __restrict__ Bh, int KT,
                       const float* __restrict__ bL, const float* __restrict__ bR,
                       unsigned short* __restrict__ C, int M) {
    __shared__ unsigned short Bs[16384];      // 32 KB: [4nt][8kt][512]
    const int p = blockIdx.x;
    const int strip = ((p >> 6) << 3) + (p & 7);
    if (strip * 256 >= M) return;             // padded tail
    const int slice = (p >> 3) & 7;
    const int m0 = strip * 256;
    const int tid = threadIdx.x;
    const int lane = tid & 63, w = tid >> 6;
    const int r15 = lane & 15, kq = lane >> 4;
    const size_t sliceBase = (size_t)slice * 4 * KT * 64;   // uint4 units
    const size_t tileStride = (size_t)KT * 512;             // shorts per 16-row tile

    f32x4 acc[2][4];
#pragma unroll
    for (int m = 0; m < 2; ++m)
#pragma unroll
        for (int n = 0; n < 4; ++n) acc[m][n] = (f32x4){0.f, 0.f, 0.f, 0.f};

    const unsigned short* aPtr[2];
#pragma unroll
    for (int m = 0; m < 2; ++m)
        aPtr[m] = Atile + (size_t)(strip * 16 + w * 2 + m) * tileStride + lane * 8;

    // ---- prime 2-deep A pipeline ----
    bf16x8 curH[2], midH[2];
#pragma unroll
    for (int m = 0; m < 2; ++m) {
        curH[m] = *(const bf16x8*)(aPtr[m]);
        midH[m] = *(const bf16x8*)(aPtr[m] + 512);
    }

    const int nchunks = KT / 8;
    for (int kc = 0; kc < nchunks; ++kc) {
        // ---- fill B LDS for this 8-ktile chunk (2048 uint4, 512 thr) ----
        {
            const uint4* gh = (const uint4*)Bh + sliceBase;
            uint4* lh = (uint4*)Bs;
#pragma unroll
            for (int i = 0; i < 4; ++i) {
                int u = i * 512 + tid;
                int nt = u >> 9;
                int ktl = (u & 511) >> 6, j = u & 63;
                lh[u] = gh[((size_t)nt * KT + kc * 8 + ktl) * 64 + j];
            }
        }
        __syncthreads();

#pragma unroll
        for (int ktl = 0; ktl < 8; ++ktl) {
            const int kt = kc * 8 + ktl;
            bf16x8 nxtH[2];
            const bool hn2 = (kt + 2 < KT);
            if (hn2) {
#pragma unroll
                for (int m = 0; m < 2; ++m)
                    nxtH[m] = *(const bf16x8*)(aPtr[m] + (size_t)(kt + 2) * 512);
            }
#pragma unroll
            for (int n = 0; n < 4; ++n) {
                bf16x8 bh = *(const bf16x8*)&Bs[(n * 8 + ktl) * 512 + lane * 8];
#pragma unroll
                for (int m = 0; m < 2; ++m)
                    acc[m][n] = __builtin_amdgcn_mfma_f32_16x16x32_bf16(
                        curH[m], bh, acc[m][n], 0, 0, 0);
            }
#pragma unroll
            for (int m = 0; m < 2; ++m) {
                curH[m] = midH[m];
                if (hn2) midH[m] = nxtH[m];
            }
        }
        __syncthreads();
    }
    // ---- epilogue: C/D col=lane&15, row=(lane>>4)*4+reg (verified r4-r16) ----
#pragma unroll
    for (int n = 0; n < 4; ++n) {
        int gcol = slice * 64 + n * 16 + r15;
        float bv = (gcol < 256) ? bL[gcol] : bR[gcol - 256];
#pragma unroll
        for (int m = 0; m < 2; ++m) {
#pragma unroll
            for (int r = 0; r < 4; ++r) {
                int grow = m0 + w * 32 + m * 16 + kq * 4 + r;
                if (grow < M)
                    C[(size_t)grow * 512 + gcol] = f2bf(acc[m][n][r] + bv);
            }
        }
    }
}

// ================= CSR build: parallel 3-phase scan (verbatim r16) =================
#define SCAN_BLOCKS 196

__global__ void csr_count(const int* __restrict__ ei, int* __restrict__ cnt) {
    int e = blockIdx.x * 256 + threadIdx.x;
    if (e < NE) atomicAdd(&cnt[ei[NE + e]], 1);
}
__global__ void csr_bsum(const int* __restrict__ cnt, int* __restrict__ bsum) {
    __shared__ int s[256];
    int idx = blockIdx.x * 256 + threadIdx.x;
    int v = idx < NN ? cnt[idx] : 0;
    s[threadIdx.x] = v;
    __syncthreads();
    for (int d = 128; d > 0; d >>= 1) {
        if (threadIdx.x < d) s[threadIdx.x] += s[threadIdx.x + d];
        __syncthreads();
    }
    if (threadIdx.x == 0) bsum[blockIdx.x] = s[0];
}
__global__ void csr_scan_bsum(int* __restrict__ bsum) {
    __shared__ int s[256];
    int t = threadIdx.x;
    int v = t < SCAN_BLOCKS ? bsum[t] : 0;
    s[t] = v;
    __syncthreads();
    for (int d = 1; d < 256; d <<= 1) {
        int x = (t >= d) ? s[t - d] : 0;
        __syncthreads();
        s[t] += x;
        __syncthreads();
    }
    if (t < SCAN_BLOCKS) bsum[t] = s[t] - v;   // exclusive
}
__global__ void csr_apply(const int* __restrict__ cnt, const int* __restrict__ bsum,
                          int* __restrict__ off, int* __restrict__ cursor) {
    __shared__ int s[256];
    int idx = blockIdx.x * 256 + threadIdx.x;
    int v = (idx < NN) ? cnt[idx] : 0;
    s[threadIdx.x] = v;
    __syncthreads();
    for (int d = 1; d < 256; d <<= 1) {
        int x = (threadIdx.x >= d) ? s[threadIdx.x - d] : 0;
        __syncthreads();
        s[threadIdx.x] += x;
        __syncthreads();
    }
    int o = bsum[blockIdx.x] + s[threadIdx.x] - v;
    if (idx < NN) { off[idx] = o; cursor[idx] = o; }
    if (idx == NN - 1) off[NN] = o + v;
}
__global__ void csr_fill(const int* __restrict__ ei, int* __restrict__ cursor,
                         int* __restrict__ eidl) {
    int e = blockIdx.x * 256 + threadIdx.x;
    if (e < NE) {
        int d = ei[NE + e];
        int p = atomicAdd(&cursor[d], 1);
        eidl[p] = e;
    }
}

// ---------- per-edge logit partial (verbatim r6) ----------
__device__ __forceinline__ float edge_part(const float4& l, const float4& r,
                                           const float* ev, const float (*rW)[4],
                                           const float4& attv) {
    const float* lp = &l.x; const float* rp = &r.x; const float* ap = &attv.x;
    float part = 0.f;
#pragma unroll
    for (int j = 0; j < 4; ++j) {
        float ecf = 0.f;
#pragma unroll
        for (int d = 0; d < 12; ++d) ecf = fmaf(ev[d], rW[d][j], ecf);
        float mv = lp[j] + rp[j] + ecf;
        mv = mv > 0.f ? mv : SLOPE * mv;
        part = fmaf(mv, ap[j], part);
    }
    return part;
}

// ---------- fused node pass (verbatim r15/r16) ----------
template<int NHEADS, int OUTMODE>
__launch_bounds__(256)
__global__ void node_fused(const unsigned short* __restrict__ x16,
                           const int* __restrict__ off, const int* __restrict__ eidl,
                           const int* __restrict__ ei, const float* __restrict__ ea,
                           const float* __restrict__ We, int ldwe,
                           const float* __restrict__ att,
                           const float* __restrict__ bias, const float* __restrict__ gam,
                           const float* __restrict__ bet, const float* __restrict__ mu,
                           const float* __restrict__ var,
                           unsigned short* __restrict__ h1t, int hcol,
                           float* __restrict__ fout) {
    const int n = blockIdx.x * 4 + (threadIdx.x >> 6);
    const int lane = threadIdx.x & 63;
    const int cf = lane * 4;
    float rW[12][4];
#pragma unroll
    for (int d = 0; d < 12; ++d) {
        float4 w = *(const float4*)&We[(size_t)d * ldwe + cf];
        rW[d][0] = w.x; rW[d][1] = w.y; rW[d][2] = w.z; rW[d][3] = w.w;
    }
    const float4 attv = *(const float4*)&att[cf];
    float4 xr4;
    {
        ushort4 u = *(const ushort4*)(x16 + (size_t)n * 512 + 256 + cf);
        xr4 = make_float4(bf2f(u.x), bf2f(u.y), bf2f(u.z), bf2f(u.w));
    }
    float acc[4] = {0.f, 0.f, 0.f, 0.f};
    float den = 0.f;
    const int beg = off[n], end = off[n + 1];
    constexpr int RED = 64 / NHEADS;
    int k = beg;
    for (; k + 2 <= end; k += 2) {
        int e0 = eidl[k], e1 = eidl[k + 1];
        int s0 = ei[e0], s1 = ei[e1];
        float ev0[12], ev1[12];
        const float2* p0 = (const float2*)(ea + (size_t)e0 * 12);
        const float2* p1 = (const float2*)(ea + (size_t)e1 * 12);
#pragma unroll
        for (int d = 0; d < 6; ++d) {
            float2 a = p0[d], b = p1[d];
            ev0[2 * d] = a.x; ev0[2 * d + 1] = a.y;
            ev1[2 * d] = b.x; ev1[2 * d + 1] = b.y;
        }
        ushort4 u0 = *(const ushort4*)(x16 + (size_t)s0 * 512 + cf);
        ushort4 u1 = *(const ushort4*)(x16 + (size_t)s1 * 512 + cf);
        float4 l0 = make_float4(bf2f(u0.x), bf2f(u0.y), bf2f(u0.z), bf2f(u0.w));
        float4 l1 = make_float4(bf2f(u1.x), bf2f(u1.y), bf2f(u1.z), bf2f(u1.w));
        float pa = edge_part(l0, xr4, ev0, rW, attv);
        float pb = edge_part(l1, xr4, ev1, rW, attv);
#pragma unroll
        for (int o = RED / 2; o > 0; o >>= 1) {
            pa += __shfl_xor(pa, o);
            pb += __shfl_xor(pb, o);
        }
        float ex0 = __expf(pa), ex1 = __expf(pb);
        den += ex0 + ex1;
        const float* lp0 = &l0.x; const float* lp1 = &l1.x;
#pragma unroll
        for (int j = 0; j < 4; ++j)
            acc[j] = fmaf(ex0, lp0[j], fmaf(ex1, lp1[j], acc[j]));
    }
    if (k < end) {
        int e0 = eidl[k];
        int s0 = ei[e0];
        float ev0[12];
        const float2* p0 = (const float2*)(ea + (size_t)e0 * 12);
#pragma unroll
        for (int d = 0; d < 6; ++d) {
            float2 a = p0[d];
            ev0[2 * d] = a.x; ev0[2 * d + 1] = a.y;
        }
        ushort4 u0 = *(const ushort4*)(x16 + (size_t)s0 * 512 + cf);
        float4 l0 = make_float4(bf2f(u0.x), bf2f(u0.y), bf2f(u0.z), bf2f(u0.w));
        float pa = edge_part(l0, xr4, ev0, rW, attv);
#pragma unroll
        for (int o = RED / 2; o > 0; o >>= 1) pa += __shfl_xor(pa, o);
        float ex0 = __expf(pa);
        den += ex0;
        const float* lp0 = &l0.x;
#pragma unroll
        for (int j = 0; j < 4; ++j) acc[j] = fmaf(ex0, lp0[j], acc[j]);
    }
    const float inv = 1.f / (den + 1e-16f);
    float o[4];
#pragma unroll
    for (int j = 0; j < 4; ++j) {
        int c = cf + j;
        float t = fmaxf(acc[j] * inv + bias[c], 0.f);
        o[j] = (t - mu[c]) * rsqrtf(var[c] + EPSBN) * gam[c] + bet[c];
    }
    if (OUTMODE == 0) {
        ushort4 hv;
        hv.x = f2bf(o[0]); hv.y = f2bf(o[1]); hv.z = f2bf(o[2]); hv.w = f2bf(o[3]);
        const int kt = (hcol >> 5) + (cf >> 5);
        size_t idx = (size_t)(n >> 4) * 16384 + (size_t)kt * 512
                   + ((((cf >> 3) & 3) << 4) + (n & 15)) * 8 + (cf & 7);
        *(ushort4*)(h1t + idx) = hv;
    } else {
        *(float4*)(fout + (size_t)n * 256 + cf) = make_float4(o[0], o[1], o[2], o[3]);
    }
}

// ================= head MLP (verbatim r15/r16) =================
__launch_bounds__(64)
__global__ void head_mlp(const float* __restrict__ h2, const int* __restrict__ n_nodes,
                         const float* __restrict__ Wf1, const float* __restrict__ bf1,
                         const float* __restrict__ Wf2, const float* __restrict__ bf2,
                         float* __restrict__ out) {
    const int g = blockIdx.x;
    const int t = threadIdx.x;
    int acc = 0;
    for (int i = t; i <= g; i += 64) acc += n_nodes[i];
#pragma unroll
    for (int off = 32; off > 0; off >>= 1) acc += __shfl_xor(acc, off);
    const int node = acc - 1;
    __shared__ float row[256];
    for (int i = t; i < 256; i += 64) row[i] = h2[(size_t)node * 256 + i];
    __syncthreads();
    float hid = bf1[t];
    for (int k = 0; k < 256; ++k) hid = fmaf(row[k], Wf1[k * 64 + t], hid);
    hid = fmaxf(hid, 0.f);
    float p = hid * Wf2[t];
#pragma unroll
    for (int off = 32; off > 0; off >>= 1) p += __shfl_xor(p, off);
    if (t == 0) out[g] = p + bf2[0];
}

extern "C" void kernel_launch(void* const* d_in, const int* in_sizes, int n_in,
                              void* d_out, int out_size, void* d_ws, size_t ws_size,
                              hipStream_t stream) {
    const float* x   = (const float*)d_in[0];
    const int*   ei  = (const int*)d_in[1];
    const float* ea  = (const float*)d_in[2];
    const int*   nnd = (const int*)d_in[3];
    const float* Wl1 = (const float*)d_in[4];
    const float* bl1 = (const float*)d_in[5];
    const float* Wr1 = (const float*)d_in[6];
    const float* br1 = (const float*)d_in[7];
    const float* We1 = (const float*)d_in[8];
    const float* att1= (const float*)d_in[9];
    const float* b1  = (const float*)d_in[10];
    const float* g1  = (const float*)d_in[11];
    const float* be1 = (const float*)d_in[12];
    const float* m1  = (const float*)d_in[13];
    const float* v1  = (const float*)d_in[14];
    const float* Wl2 = (const float*)d_in[15];
    const float* bl2 = (const float*)d_in[16];
    const float* Wr2 = (const float*)d_in[17];
    const float* br2 = (const float*)d_in[18];
    const float* We2 = (const float*)d_in[19];
    const float* att2= (const float*)d_in[20];
    const float* b2  = (const float*)d_in[21];
    const float* g2  = (const float*)d_in[22];
    const float* be2 = (const float*)d_in[23];
    const float* m2  = (const float*)d_in[24];
    const float* v2  = (const float*)d_in[25];
    const float* Wf1 = (const float*)d_in[26];
    const float* bf1 = (const float*)d_in[27];
    const float* Wf2 = (const float*)d_in[28];
    const float* bf2 = (const float*)d_in[29];
    float* out = (float*)d_out;

    // ---- workspace (~183 MB; proven fit) ----
    const size_t XB = (size_t)NN * 512 * 2;          // 51.2 MB bf16 panel (xlr/xlr2)
    const size_t HB = (size_t)3136 * 16384 * 2;      // 102.8 MB h1 tiled bf16 / h2 f32
    const size_t XTB = (size_t)NROWT * 4096 * 2;     // 25.6 MB x tiled bf16
    const size_t WPB = (size_t)524288 * 2;           // 1 MB per weight plane
    char* ws = (char*)d_ws;
    size_t off = 0;
    unsigned short* panel = (unsigned short*)(ws + off); off += XB;
    unsigned short* h1t   = (unsigned short*)(ws + off);
    float*          h2f   = (float*)(ws + off);    off += HB;
    unsigned short* xt    = (unsigned short*)(ws + off); off += XTB;
    unsigned short* B1h = (unsigned short*)(ws + off); off += WPB;
    unsigned short* B2h = (unsigned short*)(ws + off); off += WPB;
    int* cnt    = (int*)(ws + off); off += (size_t)NN * 4;
    int* csroff = (int*)(ws + off); off += ((size_t)(NN + 1) * 4 + 15) & ~15ull;
    int* cursor = (int*)(ws + off); off += (size_t)NN * 4;
    int* eidl   = (int*)(ws + off); off += (size_t)NE * 4;
    int* bsum   = (int*)(ws + off); off += ((size_t)SCAN_BLOCKS * 4 + 15) & ~15ull;
    if (ws_size < off) {
        fill_val<<<(out_size + 255) / 256, 256, 0, stream>>>(out, out_size, 1e30f);
        return;
    }

    // ---- CSR build (parallel scan, verbatim r16) ----
    hipMemsetAsync(cnt, 0, (size_t)NN * 4, stream);
    csr_count<<<(NE + 255) / 256, 256, 0, stream>>>(ei, cnt);
    csr_bsum<<<SCAN_BLOCKS, 256, 0, stream>>>(cnt, bsum);
    csr_scan_bsum<<<1, 256, 0, stream>>>(bsum);
    csr_apply<<<SCAN_BLOCKS, 256, 0, stream>>>(cnt, bsum, csroff, cursor);
    csr_fill<<<(NE + 255) / 256, 256, 0, stream>>>(ei, cursor, eidl);

    // ---- weight + x prep ----
    wprep1t<<<2048, 256, 0, stream>>>(Wl1, Wr1, B1h);
    wprep2t<<<2048, 256, 0, stream>>>(Wl2, Wr2, B2h);
    xprep<<<(NROWT * 16 * 32 + 255) / 256, 256, 0, stream>>>(x, xt);

    // strip-clustered 1D grid: 196 strips of 256 rows -> pad to 200 (25 groups of 8)
    const int gemmBlocks = 25 * 64;   // 1600
    const int nodeBlocks = NN / 4;

    // ================= layer 1, per head =================
    for (int h = 0; h < NH; ++h) {
        gemm_t<<<gemmBlocks, 512, 0, stream>>>(
            xt, B1h + (size_t)h * 131072, 8, bl1 + h * 256, br1 + h * 256, panel, NN);
        node_fused<1, 0><<<nodeBlocks, 256, 0, stream>>>(
            panel, csroff, eidl, ei, ea, We1 + h * 256, 1024, att1 + h * 256,
            b1 + h * 256, g1 + h * 256, be1 + h * 256, m1 + h * 256, v1 + h * 256,
            h1t, h * 256, nullptr);
    }

    // ================= layer 2: single K=1024 GEMM =================
    gemm_t<<<gemmBlocks, 512, 0, stream>>>(
        h1t, B2h, 32, bl2, br2, panel, NN);
    node_fused<4, 1><<<nodeBlocks, 256, 0, stream>>>(
        panel, csroff, eidl, ei, ea, We2, 256, att2, b2, g2, be2, m2, v2,
        nullptr, 0, h2f);

    head_mlp<<<NG, 64, 0, stream>>>(h2f, nnd, Wf1, bf1, Wf2, bf2, out);
}